// Round 1
// baseline (535.553 us; speedup 1.0000x reference)
//
#include <hip/hip_runtime.h>
#include <hip/hip_bf16.h>
#include <cstdint>

typedef __attribute__((ext_vector_type(8))) short short8;
typedef __attribute__((ext_vector_type(4))) float f32x4;
typedef unsigned short u16;
typedef unsigned int u32;

// ---------- helpers ----------
__device__ __forceinline__ u16 f2bf(float f) {
    union { float f; u32 u; } v; v.f = f;
    u32 u = v.u;
    u = (u + 0x7fffu + ((u >> 16) & 1u)) >> 16;
    return (u16)u;
}

// ---------- kernel 0: W_comb = W_mh @ W_in (bf16), cast W_fc -> bf16 ----------
__global__ void prep_kernel(const float* __restrict__ W_in,
                            const float* __restrict__ W_mh,
                            const float* __restrict__ W_fc,
                            u16* __restrict__ wcomb, u16* __restrict__ wfc16) {
    int idx = blockIdx.x * 256 + threadIdx.x;
    if (idx < 1024 * 64) {
        int f = idx >> 6, i = idx & 63;
        float acc = 0.f;
        for (int e = 0; e < 128; ++e)
            acc += W_mh[f * 128 + e] * W_in[e * 64 + i];
        wcomb[idx] = f2bf(acc);
    }
    int idx2 = idx - 65536;
    if (idx2 >= 0 && idx2 < 128 * 1024)
        wfc16[idx2] = f2bf(W_fc[idx2]);
}

// ---------- kernel 1: Qe = Q @ W_in^T (fp32 residual) ----------
__global__ void qe_kernel(const float* __restrict__ Q,
                          const float* __restrict__ W_in,
                          float* __restrict__ Qe) {
    int idx = blockIdx.x * 256 + threadIdx.x;   // 16384*128 outputs
    int R = idx >> 7, e = idx & 127;
    const float* q = Q + (size_t)R * 64;
    const float* w = W_in + (size_t)e * 64;
    float acc = 0.f;
#pragma unroll
    for (int i = 0; i < 64; i += 4) {
        float4 a = *(const float4*)(q + i);
        float4 b = *(const float4*)(w + i);
        acc += a.x * b.x + a.y * b.y + a.z * b.z + a.w * b.w;
    }
    Qe[idx] = acc;
}

// ---------- kernel 2: q/k/v = X @ W_comb^T, bf16, v stored transposed ----------
__global__ __launch_bounds__(256) void qkv_kernel(
    const float* __restrict__ Q, const float* __restrict__ K,
    const float* __restrict__ V, const u16* __restrict__ wcomb,
    u16* __restrict__ qb, u16* __restrict__ kb, u16* __restrict__ vT) {
    int w = threadIdx.x >> 6, lane = threadIdx.x & 63;
    int g = lane >> 4, c15 = lane & 15;
    int tensor = blockIdx.z;
    const float* X = tensor == 0 ? Q : (tensor == 1 ? K : V);

    int Rrow = blockIdx.x * 64 + w * 16 + c15;          // A-operand row
    short8 af[2];
#pragma unroll
    for (int c = 0; c < 2; ++c) {
        const float* p = X + (size_t)Rrow * 64 + 8 * g + 32 * c;
        float4 fa = *(const float4*)(p);
        float4 fb = *(const float4*)(p + 4);
        short8 a;
        a[0] = (short)f2bf(fa.x); a[1] = (short)f2bf(fa.y);
        a[2] = (short)f2bf(fa.z); a[3] = (short)f2bf(fa.w);
        a[4] = (short)f2bf(fb.x); a[5] = (short)f2bf(fb.y);
        a[6] = (short)f2bf(fb.z); a[7] = (short)f2bf(fb.w);
        af[c] = a;
    }
    int colbase = blockIdx.y * 256;
    f32x4 acc[16];
#pragma unroll
    for (int i = 0; i < 16; ++i) acc[i] = {0.f, 0.f, 0.f, 0.f};
#pragma unroll
    for (int cb = 0; cb < 16; ++cb) {
        int col = colbase + cb * 16 + c15;
#pragma unroll
        for (int c = 0; c < 2; ++c) {
            short8 bfr = *(const short8*)(wcomb + (size_t)col * 64 + 8 * g + 32 * c);
            acc[cb] = __builtin_amdgcn_mfma_f32_16x16x32_bf16(af[c], bfr, acc[cb], 0, 0, 0);
        }
    }
    int Rbase = blockIdx.x * 64 + w * 16 + 4 * g;       // C rows
    u16* outqk = tensor == 0 ? qb : kb;
#pragma unroll
    for (int cb = 0; cb < 16; ++cb) {
        int col = colbase + cb * 16 + c15;
        int h = col >> 7, d = col & 127;
#pragma unroll
        for (int r = 0; r < 4; ++r) {
            int R = Rbase + r;
            int b = R >> 11, s = R & 2047;
            u16 val = f2bf(acc[cb][r]);
            if (tensor < 2)
                outqk[((size_t)(b * 8 + h) * 2048 + s) * 128 + d] = val;
            else
                vT[((size_t)(b * 8 + h) * 128 + d) * 2048 + s] = val;
        }
    }
}

// ---------- kernel 3: flash attention ----------
__global__ __launch_bounds__(256) void attn_kernel(
    const u16* __restrict__ qbuf, const u16* __restrict__ kbuf,
    const u16* __restrict__ vTbuf, const float* __restrict__ qmask,
    u16* __restrict__ mha) {
    __shared__ __align__(16) u16 kt[64 * 136];   // K tile [64 keys][128+8 pad]
    __shared__ __align__(16) u16 vt[128 * 72];   // V^T tile [128 d][64+8 pad]
    __shared__ __align__(16) u16 pl[4 * 16 * 72];// P per wave [16 q][64+8 pad]
    __shared__ float am[64];                     // additive mask

    int w = threadIdx.x >> 6, lane = threadIdx.x & 63;
    int g = lane >> 4, c15 = lane & 15;
    int qt = blockIdx.x, h = blockIdx.y, b = blockIdx.z;
    int bh = b * 8 + h;
    const u16* qrow = qbuf + ((size_t)bh * 2048 + qt * 64) * 128;
    const u16* krow = kbuf + (size_t)bh * 2048 * 128;
    const u16* vrow = vTbuf + (size_t)bh * 128 * 2048;

    short8 qf[4];
#pragma unroll
    for (int c = 0; c < 4; ++c)
        qf[c] = *(const short8*)(qrow + (size_t)(w * 16 + c15) * 128 + 8 * g + 32 * c);

    f32x4 o[8];
#pragma unroll
    for (int i = 0; i < 8; ++i) o[i] = {0.f, 0.f, 0.f, 0.f};
    float m[4], l[4];
#pragma unroll
    for (int r = 0; r < 4; ++r) { m[r] = -1e30f; l[r] = 0.f; }

    const float invT = 0.08838834764831845f;     // 1/sqrt(128)

    for (int t = 0; t < 32; ++t) {
        __syncthreads();
        // cooperative K tile load (64x128 bf16, 16B chunks)
#pragma unroll
        for (int i = 0; i < 4; ++i) {
            int chunk = threadIdx.x + i * 256;
            int row = chunk >> 4, cc = chunk & 15;
            *(uint4*)(kt + row * 136 + cc * 8) =
                *(const uint4*)(krow + ((size_t)(t * 64 + row)) * 128 + cc * 8);
        }
        // cooperative V^T tile load (128x64 bf16)
#pragma unroll
        for (int i = 0; i < 4; ++i) {
            int chunk = threadIdx.x + i * 256;
            int row = chunk >> 3, cc = chunk & 7;
            *(uint4*)(vt + row * 72 + cc * 8) =
                *(const uint4*)(vrow + (size_t)row * 2048 + t * 64 + cc * 8);
        }
        if (threadIdx.x < 64)
            am[threadIdx.x] = (1.0f - qmask[b * 2048 + t * 64 + threadIdx.x]) * (-1e30f);
        __syncthreads();

        // S = (q/T) k^T + mask
        float sm[4][4];
#pragma unroll
        for (int kb2 = 0; kb2 < 4; ++kb2) {
            f32x4 sacc = {0.f, 0.f, 0.f, 0.f};
            int key = kb2 * 16 + c15;
#pragma unroll
            for (int c = 0; c < 4; ++c) {
                short8 kf = *(const short8*)(kt + key * 136 + 8 * g + 32 * c);
                sacc = __builtin_amdgcn_mfma_f32_16x16x32_bf16(qf[c], kf, sacc, 0, 0, 0);
            }
            float amv = am[key];
#pragma unroll
            for (int r = 0; r < 4; ++r)
                sm[kb2][r] = fmaf(sacc[r], invT, amv);
        }
        // online softmax (rows live in 16-lane groups)
        float corr[4];
#pragma unroll
        for (int r = 0; r < 4; ++r) {
            float v = fmaxf(fmaxf(sm[0][r], sm[1][r]), fmaxf(sm[2][r], sm[3][r]));
#pragma unroll
            for (int dd = 1; dd < 16; dd <<= 1)
                v = fmaxf(v, __shfl_xor(v, dd));
            float mn = fmaxf(m[r], v);
            corr[r] = __expf(m[r] - mn);
            m[r] = mn;
        }
        float p[4][4];
#pragma unroll
        for (int kb2 = 0; kb2 < 4; ++kb2)
#pragma unroll
            for (int r = 0; r < 4; ++r)
                p[kb2][r] = __expf(sm[kb2][r] - m[r]);
#pragma unroll
        for (int r = 0; r < 4; ++r) {
            float v = p[0][r] + p[1][r] + p[2][r] + p[3][r];
#pragma unroll
            for (int dd = 1; dd < 16; dd <<= 1)
                v += __shfl_xor(v, dd);
            l[r] = l[r] * corr[r] + v;
        }
#pragma unroll
        for (int i = 0; i < 8; ++i)
#pragma unroll
            for (int r = 0; r < 4; ++r)
                o[i][r] *= corr[r];
        // P -> bf16 -> per-wave LDS
        u16* pw = pl + w * (16 * 72);
#pragma unroll
        for (int kb2 = 0; kb2 < 4; ++kb2)
#pragma unroll
            for (int r = 0; r < 4; ++r)
                pw[(4 * g + r) * 72 + kb2 * 16 + c15] = f2bf(p[kb2][r]);
        asm volatile("s_waitcnt lgkmcnt(0)" ::: "memory");
        // O += P @ V
#pragma unroll
        for (int c = 0; c < 2; ++c) {
            short8 pa = *(const short8*)(pw + c15 * 72 + 8 * g + 32 * c);
#pragma unroll
            for (int db = 0; db < 8; ++db) {
                short8 vf = *(const short8*)(vt + (db * 16 + c15) * 72 + 8 * g + 32 * c);
                o[db] = __builtin_amdgcn_mfma_f32_16x16x32_bf16(pa, vf, o[db], 0, 0, 0);
            }
        }
    }
    // epilogue: normalize + scatter into "faithful reshape" layout
    float invl[4];
#pragma unroll
    for (int r = 0; r < 4; ++r) invl[r] = 1.0f / l[r];
#pragma unroll
    for (int db = 0; db < 8; ++db) {
#pragma unroll
        for (int r = 0; r < 4; ++r) {
            int sg = qt * 64 + w * 16 + 4 * g + r;
            int srow = h * 256 + (sg >> 3);
            int f = (sg & 7) * 128 + db * 16 + c15;
            mha[((size_t)b * 2048 + srow) * 1024 + f] = f2bf(o[db][r] * invl[r]);
        }
    }
}

// ---------- kernel 4: out = mha @ W_fc^T + Qe, then LayerNorm ----------
__global__ __launch_bounds__(256) void final_kernel(
    const u16* __restrict__ mha, const u16* __restrict__ wfc16,
    const float* __restrict__ Qe, const float* __restrict__ ln_g,
    const float* __restrict__ ln_b, float* __restrict__ out) {
    int w = threadIdx.x >> 6, lane = threadIdx.x & 63;
    int g = lane >> 4, c15 = lane & 15;
    int rbase = blockIdx.x * 64 + w * 16;
    f32x4 acc[8];
#pragma unroll
    for (int i = 0; i < 8; ++i) acc[i] = {0.f, 0.f, 0.f, 0.f};
    for (int kc = 0; kc < 32; ++kc) {
        short8 af = *(const short8*)(mha + (size_t)(rbase + c15) * 1024 + 8 * g + 32 * kc);
#pragma unroll
        for (int db = 0; db < 8; ++db) {
            short8 bfr = *(const short8*)(wfc16 + (size_t)(db * 16 + c15) * 1024 + 8 * g + 32 * kc);
            acc[db] = __builtin_amdgcn_mfma_f32_16x16x32_bf16(af, bfr, acc[db], 0, 0, 0);
        }
    }
    int R0 = rbase + 4 * g;
    float x[8][4];
    float sum[4] = {0, 0, 0, 0}, sq[4] = {0, 0, 0, 0};
#pragma unroll
    for (int db = 0; db < 8; ++db) {
        int e = db * 16 + c15;
#pragma unroll
        for (int r = 0; r < 4; ++r) {
            float v = acc[db][r] + Qe[(size_t)(R0 + r) * 128 + e];
            x[db][r] = v;
            sum[r] += v;
            sq[r] += v * v;
        }
    }
#pragma unroll
    for (int r = 0; r < 4; ++r) {
#pragma unroll
        for (int dd = 1; dd < 16; dd <<= 1) {
            sum[r] += __shfl_xor(sum[r], dd);
            sq[r]  += __shfl_xor(sq[r], dd);
        }
    }
#pragma unroll
    for (int db = 0; db < 8; ++db) {
        int e = db * 16 + c15;
        float gg = ln_g[e], bb = ln_b[e];
#pragma unroll
        for (int r = 0; r < 4; ++r) {
            float mean = sum[r] * (1.0f / 128.0f);
            float var = sq[r] * (1.0f / 128.0f) - mean * mean;
            float rstd = rsqrtf(var + 1e-6f);
            out[(size_t)(R0 + r) * 128 + e] = (x[db][r] - mean) * rstd * gg + bb;
        }
    }
}

// ---------- launcher ----------
extern "C" void kernel_launch(void* const* d_in, const int* in_sizes, int n_in,
                              void* d_out, int out_size, void* d_ws, size_t ws_size,
                              hipStream_t stream) {
    const float* Q     = (const float*)d_in[0];
    const float* K     = (const float*)d_in[1];
    const float* V     = (const float*)d_in[2];
    const float* QMask = (const float*)d_in[3];
    const float* W_in  = (const float*)d_in[4];
    const float* W_mh  = (const float*)d_in[5];
    const float* W_fc  = (const float*)d_in[6];
    const float* ln_g  = (const float*)d_in[7];
    const float* ln_b  = (const float*)d_in[8];
    float* out = (float*)d_out;

    char* ws = (char*)d_ws;
    u16*   wcomb = (u16*)(ws);                   // 1024x64 bf16   = 131072 B
    u16*   wfc16 = (u16*)(ws + 131072);          // 128x1024 bf16  = 262144 B
    float* Qe    = (float*)(ws + 393216);        // 16384x128 f32  = 8388608 B
    u16*   qb    = (u16*)(ws + 8781824);         // [B,H,S,128] bf16 = 33554432 B
    u16*   kb    = (u16*)(ws + 42336256);        // same
    u16*   vT    = (u16*)(ws + 75890688);        // [B,H,128,S] bf16
    u16*   mha   = (u16*)(ws + 109445120);       // [B,2048,1024] bf16

    hipLaunchKernelGGL(prep_kernel, dim3(768), dim3(256), 0, stream,
                       W_in, W_mh, W_fc, wcomb, wfc16);
    hipLaunchKernelGGL(qe_kernel, dim3(8192), dim3(256), 0, stream, Q, W_in, Qe);
    hipLaunchKernelGGL(qkv_kernel, dim3(256, 4, 3), dim3(256), 0, stream,
                       Q, K, V, wcomb, qb, kb, vT);
    hipLaunchKernelGGL(attn_kernel, dim3(32, 8, 8), dim3(256), 0, stream,
                       qb, kb, vT, QMask, mha);
    hipLaunchKernelGGL(final_kernel, dim3(256), dim3(256), 0, stream,
                       mha, wfc16, Qe, ln_g, ln_b, out);
}

// Round 2
// 391.093 us; speedup vs baseline: 1.3694x; 1.3694x over previous
//
#include <hip/hip_runtime.h>
#include <hip/hip_bf16.h>
#include <cstdint>

typedef __attribute__((ext_vector_type(8))) short short8;
typedef __attribute__((ext_vector_type(4))) float f32x4;
typedef unsigned short u16;
typedef unsigned int u32;

__device__ __forceinline__ u16 f2bf(float f) {
    union { float f; u32 u; } v; v.f = f;
    u32 u = v.u;
    u = (u + 0x7fffu + ((u >> 16) & 1u)) >> 16;
    return (u16)u;
}

__device__ __forceinline__ void gload_lds16(const u16* g, u16* l) {
    __builtin_amdgcn_global_load_lds((const __attribute__((address_space(1))) void*)g,
                                     (__attribute__((address_space(3))) void*)l, 16, 0, 0);
}

// ---------- kernel 0: W_comb = W_mh @ W_in (bf16), cast W_fc -> bf16 ----------
__global__ void prep_kernel(const float* __restrict__ W_in,
                            const float* __restrict__ W_mh,
                            const float* __restrict__ W_fc,
                            u16* __restrict__ wcomb, u16* __restrict__ wfc16) {
    int idx = blockIdx.x * 256 + threadIdx.x;
    if (idx < 1024 * 64) {
        int f = idx >> 6, i = idx & 63;
        float acc = 0.f;
        for (int e = 0; e < 128; ++e)
            acc += W_mh[f * 128 + e] * W_in[e * 64 + i];
        wcomb[idx] = f2bf(acc);
    }
    int idx2 = idx - 65536;
    if (idx2 >= 0 && idx2 < 128 * 1024)
        wfc16[idx2] = f2bf(W_fc[idx2]);
}

// ---------- kernel 0b: per-batch stable compaction scan of QMask ----------
__global__ void mask_scan(const float* __restrict__ qmask,
                          u16* __restrict__ pos, int* __restrict__ cnt) {
    int b = blockIdx.x, t = threadIdx.x;        // 64 threads
    int base = b * 2048 + t * 32;
    int c = 0;
#pragma unroll
    for (int i = 0; i < 32; ++i) c += (qmask[base + i] != 0.0f) ? 1 : 0;
    int inc = c;
#pragma unroll
    for (int dd = 1; dd < 64; dd <<= 1) {
        int v = __shfl_up(inc, dd);
        if (t >= dd) inc += v;
    }
    int run = inc - c;
#pragma unroll
    for (int i = 0; i < 32; ++i) {
        bool mk = (qmask[base + i] != 0.0f);
        pos[base + i] = mk ? (u16)run : (u16)0xFFFF;
        run += mk ? 1 : 0;
    }
    if (t == 63) cnt[b] = inc;
}

// ---------- kernel 1: Qe = Q @ W_in^T (fp32 residual) ----------
__global__ void qe_kernel(const float* __restrict__ Q,
                          const float* __restrict__ W_in,
                          float* __restrict__ Qe) {
    int idx = blockIdx.x * 256 + threadIdx.x;
    int R = idx >> 7, e = idx & 127;
    const float* q = Q + (size_t)R * 64;
    const float* w = W_in + (size_t)e * 64;
    float acc = 0.f;
#pragma unroll
    for (int i = 0; i < 64; i += 4) {
        float4 a = *(const float4*)(q + i);
        float4 b = *(const float4*)(w + i);
        acc += a.x * b.x + a.y * b.y + a.z * b.z + a.w * b.w;
    }
    Qe[idx] = acc;
}

// ---------- kernel 2: q/k/v projections; q scaled by 1/sqrt(128); k,v compacted ----------
__global__ __launch_bounds__(256) void qkv_kernel(
    const float* __restrict__ Q, const float* __restrict__ K,
    const float* __restrict__ V, const u16* __restrict__ wcomb,
    const u16* __restrict__ pos,
    u16* __restrict__ qb, u16* __restrict__ kb, u16* __restrict__ vrow) {
    int w = threadIdx.x >> 6, lane = threadIdx.x & 63;
    int g = lane >> 4, c15 = lane & 15;
    int tensor = blockIdx.z;
    const float* X = tensor == 0 ? Q : (tensor == 1 ? K : V);

    int Rrow = blockIdx.x * 64 + w * 16 + c15;
    short8 af[2];
#pragma unroll
    for (int c = 0; c < 2; ++c) {
        const float* p = X + (size_t)Rrow * 64 + 8 * g + 32 * c;
        float4 fa = *(const float4*)(p);
        float4 fb = *(const float4*)(p + 4);
        short8 a;
        a[0] = (short)f2bf(fa.x); a[1] = (short)f2bf(fa.y);
        a[2] = (short)f2bf(fa.z); a[3] = (short)f2bf(fa.w);
        a[4] = (short)f2bf(fb.x); a[5] = (short)f2bf(fb.y);
        a[6] = (short)f2bf(fb.z); a[7] = (short)f2bf(fb.w);
        af[c] = a;
    }
    int colbase = blockIdx.y * 256;
    f32x4 acc[16];
#pragma unroll
    for (int i = 0; i < 16; ++i) acc[i] = {0.f, 0.f, 0.f, 0.f};
#pragma unroll
    for (int cb = 0; cb < 16; ++cb) {
        int col = colbase + cb * 16 + c15;
#pragma unroll
        for (int c = 0; c < 2; ++c) {
            short8 bfr = *(const short8*)(wcomb + (size_t)col * 64 + 8 * g + 32 * c);
            acc[cb] = __builtin_amdgcn_mfma_f32_16x16x32_bf16(af[c], bfr, acc[cb], 0, 0, 0);
        }
    }
    int Rbase = blockIdx.x * 64 + w * 16 + 4 * g;
    const float invT = 0.08838834764831845f;    // 1/sqrt(128)
    if (tensor == 0) {
#pragma unroll
        for (int cb = 0; cb < 16; ++cb) {
            int col = colbase + cb * 16 + c15;
            int h = col >> 7, d = col & 127;
#pragma unroll
            for (int r = 0; r < 4; ++r) {
                int R = Rbase + r;
                int b = R >> 11, s = R & 2047;
                qb[((size_t)(b * 8 + h) * 2048 + s) * 128 + d] = f2bf(acc[cb][r] * invT);
            }
        }
    } else {
        u16 pv[4];
#pragma unroll
        for (int r = 0; r < 4; ++r) pv[r] = pos[Rbase + r];
        u16* dstbuf = (tensor == 1) ? kb : vrow;
#pragma unroll
        for (int cb = 0; cb < 16; ++cb) {
            int col = colbase + cb * 16 + c15;
            int h = col >> 7, d = col & 127;
#pragma unroll
            for (int r = 0; r < 4; ++r) {
                if (pv[r] == 0xFFFF) continue;
                int b = (Rbase + r) >> 11;
                dstbuf[((size_t)(b * 8 + h) * 2048 + pv[r]) * 128 + d] = f2bf(acc[cb][r]);
            }
        }
    }
}

// ---------- kernel 2b: transpose compacted V rows -> vT[bh][128][2048] ----------
__global__ __launch_bounds__(256) void vtrans_kernel(
    const u16* __restrict__ vrow, const int* __restrict__ cnt,
    u16* __restrict__ vT) {
    int t = blockIdx.x, bh = blockIdx.y, b = bh >> 3;
    int L = cnt[b];
    if (t * 64 >= L) return;
    __shared__ __align__(16) u16 tile[64][136];
    const u16* src = vrow + ((size_t)bh * 2048 + t * 64) * 128;
#pragma unroll
    for (int i = 0; i < 4; ++i) {
        int chunk = threadIdx.x + i * 256;
        int row = chunk >> 4, cc = chunk & 15;
        uint4 val = {0, 0, 0, 0};
        if (t * 64 + row < L)                    // zero tail: 0*NaN would poison PV
            val = *(const uint4*)(src + (size_t)row * 128 + cc * 8);
        *(uint4*)(&tile[row][cc * 8]) = val;
    }
    __syncthreads();
    int d = threadIdx.x >> 1, half = threadIdx.x & 1;
    u16* dst = vT + ((size_t)bh * 128 + d) * 2048 + t * 64 + half * 32;
#pragma unroll
    for (int jc = 0; jc < 4; ++jc) {
        union { uint4 v; u16 s[8]; } u;
#pragma unroll
        for (int jj = 0; jj < 8; ++jj) u.s[jj] = tile[half * 32 + jc * 8 + jj][d];
        *(uint4*)(dst + jc * 8) = u.v;
    }
}

// ---------- kernel 3: flash attention over compacted keys ----------
__global__ __launch_bounds__(256) void attn_kernel(
    const u16* __restrict__ qbuf, const u16* __restrict__ kbuf,
    const u16* __restrict__ vTbuf, const int* __restrict__ cnt,
    u16* __restrict__ mha) {
    __shared__ __align__(16) u16 kt[2][64 * 128];   // linear, XOR-swizzled via source
    __shared__ __align__(16) u16 vt[2][128 * 64];
    __shared__ __align__(16) u16 pl[4 * 16 * 64];   // per-wave P, chunk-swizzled

    const int w = threadIdx.x >> 6, lane = threadIdx.x & 63;
    const int gq = lane >> 4, c15 = lane & 15;
    const int qt = blockIdx.x, h = blockIdx.y, b = blockIdx.z;
    const int bh = b * 8 + h;
    const int L = cnt[b];
    const int nt = (L + 63) >> 6;

    const u16* qrow = qbuf + ((size_t)bh * 2048 + qt * 64) * 128;
    const u16* kbbh = kbuf + (size_t)bh * 2048 * 128;
    const u16* vTbh = vTbuf + (size_t)bh * 128 * 2048;
    u16* plw = pl + w * 1024;

    short8 qf[4];
#pragma unroll
    for (int c = 0; c < 4; ++c)
        qf[c] = *(const short8*)(qrow + (size_t)(w * 16 + c15) * 128 + 8 * gq + 32 * c);

    f32x4 o[8];
#pragma unroll
    for (int i = 0; i < 8; ++i) o[i] = {0.f, 0.f, 0.f, 0.f};
    float m[4], l[4];
#pragma unroll
    for (int r = 0; r < 4; ++r) { m[r] = -1e30f; l[r] = 0.f; }

    // stage tile tt into buffer buf: linear LDS dest + inverse-swizzled source (rule 21)
    auto stage = [&](int buf, int tt) {
#pragma unroll
        for (int c = 0; c < 4; ++c) {           // K: 4 rows/wave/call, 16 rows/call total
            int rl = c * 16 + w * 4 + (lane >> 4);
            int chunk = (lane & 15) ^ (rl & 7);
            gload_lds16(kbbh + ((size_t)(tt * 64 + rl)) * 128 + chunk * 8,
                        &kt[buf][(c * 16 + w * 4) * 128]);
        }
#pragma unroll
        for (int c = 0; c < 4; ++c) {           // V^T: 8 d-rows/wave/call
            int dl = c * 32 + w * 8 + (lane >> 3);
            int chunk = (lane & 7) ^ (dl & 7);
            gload_lds16(vTbh + (size_t)dl * 2048 + tt * 64 + chunk * 8,
                        &vt[buf][(c * 32 + w * 8) * 64]);
        }
    };

    int cur = 0;
    stage(0, 0);
    __syncthreads();                            // drains vmcnt(0) before barrier

    for (int t = 0; t < nt; ++t) {
        if (t + 1 < nt) stage(cur ^ 1, t + 1);  // prefetch overlaps compute
        const u16* ktb = kt[cur];
        const u16* vtb = vt[cur];
        bool last = (t == nt - 1);

        float sm[4][4];
#pragma unroll
        for (int k2 = 0; k2 < 4; ++k2) {
            f32x4 sacc = {0.f, 0.f, 0.f, 0.f};
            int key = k2 * 16 + c15;
            const u16* kr = ktb + key * 128;
#pragma unroll
            for (int c = 0; c < 4; ++c) {
                short8 kf = *(const short8*)(kr + (((gq + 4 * c) ^ (key & 7)) << 3));
                sacc = __builtin_amdgcn_mfma_f32_16x16x32_bf16(qf[c], kf, sacc, 0, 0, 0);
            }
            bool maskout = last && (t * 64 + key >= L);
#pragma unroll
            for (int r = 0; r < 4; ++r)
                sm[k2][r] = maskout ? -1e30f : sacc[r];   // replace (kills tail NaN/Inf)
        }
        // online softmax with defer-max (THR=8)
        float pmax[4];
#pragma unroll
        for (int r = 0; r < 4; ++r) {
            float v = fmaxf(fmaxf(sm[0][r], sm[1][r]), fmaxf(sm[2][r], sm[3][r]));
#pragma unroll
            for (int dd = 1; dd < 16; dd <<= 1)
                v = fmaxf(v, __shfl_xor(v, dd));
            pmax[r] = v;
        }
        bool ok = true;
#pragma unroll
        for (int r = 0; r < 4; ++r) ok = ok && (pmax[r] - m[r] <= 8.0f);
        if (!__all(ok)) {
#pragma unroll
            for (int r = 0; r < 4; ++r) {
                float mn = fmaxf(m[r], pmax[r]);
                float corr = __expf(m[r] - mn);
                m[r] = mn;
                l[r] *= corr;
#pragma unroll
                for (int db = 0; db < 8; ++db) o[db][r] *= corr;
            }
        }
        float p[4][4];
#pragma unroll
        for (int k2 = 0; k2 < 4; ++k2)
#pragma unroll
            for (int r = 0; r < 4; ++r)
                p[k2][r] = __expf(sm[k2][r] - m[r]);
#pragma unroll
        for (int r = 0; r < 4; ++r) {
            float v = p[0][r] + p[1][r] + p[2][r] + p[3][r];
#pragma unroll
            for (int dd = 1; dd < 16; dd <<= 1)
                v += __shfl_xor(v, dd);
            l[r] += v;
        }
        // P -> bf16 -> per-wave LDS (chunk-XOR swizzle)
#pragma unroll
        for (int k2 = 0; k2 < 4; ++k2)
#pragma unroll
            for (int r = 0; r < 4; ++r) {
                int row = 4 * gq + r;
                int ci = (k2 * 2 + (c15 >> 3)) ^ (row & 7);
                plw[row * 64 + ci * 8 + (c15 & 7)] = f2bf(p[k2][r]);
            }
        asm volatile("s_waitcnt lgkmcnt(0)" ::: "memory");
        // O += P @ V
#pragma unroll
        for (int c = 0; c < 2; ++c) {
            short8 pa = *(const short8*)(plw + c15 * 64 + (((gq + 4 * c) ^ (c15 & 7)) << 3));
#pragma unroll
            for (int db = 0; db < 8; ++db) {
                int d = db * 16 + c15;
                short8 vf = *(const short8*)(vtb + d * 64 + (((gq + 4 * c) ^ (d & 7)) << 3));
                o[db] = __builtin_amdgcn_mfma_f32_16x16x32_bf16(pa, vf, o[db], 0, 0, 0);
            }
        }
        __syncthreads();                        // drains prefetch vmcnt + publishes buffer
        cur ^= 1;
    }
    // epilogue: normalize + scatter into "faithful reshape" layout
    float invl[4];
#pragma unroll
    for (int r = 0; r < 4; ++r) invl[r] = 1.0f / l[r];
#pragma unroll
    for (int db = 0; db < 8; ++db) {
#pragma unroll
        for (int r = 0; r < 4; ++r) {
            int sg = qt * 64 + w * 16 + 4 * gq + r;
            int srow = h * 256 + (sg >> 3);
            int f = (sg & 7) * 128 + db * 16 + c15;
            mha[((size_t)b * 2048 + srow) * 1024 + f] = f2bf(o[db][r] * invl[r]);
        }
    }
}

// ---------- kernel 4: out = mha @ W_fc^T + Qe, then LayerNorm ----------
__global__ __launch_bounds__(256) void final_kernel(
    const u16* __restrict__ mha, const u16* __restrict__ wfc16,
    const float* __restrict__ Qe, const float* __restrict__ ln_g,
    const float* __restrict__ ln_b, float* __restrict__ out) {
    int w = threadIdx.x >> 6, lane = threadIdx.x & 63;
    int g = lane >> 4, c15 = lane & 15;
    int rbase = blockIdx.x * 64 + w * 16;
    f32x4 acc[8];
#pragma unroll
    for (int i = 0; i < 8; ++i) acc[i] = {0.f, 0.f, 0.f, 0.f};
    for (int kc = 0; kc < 32; ++kc) {
        short8 af = *(const short8*)(mha + (size_t)(rbase + c15) * 1024 + 8 * g + 32 * kc);
#pragma unroll
        for (int db = 0; db < 8; ++db) {
            short8 bfr = *(const short8*)(wfc16 + (size_t)(db * 16 + c15) * 1024 + 8 * g + 32 * kc);
            acc[db] = __builtin_amdgcn_mfma_f32_16x16x32_bf16(af, bfr, acc[db], 0, 0, 0);
        }
    }
    int R0 = rbase + 4 * g;
    float x[8][4];
    float sum[4] = {0, 0, 0, 0}, sq[4] = {0, 0, 0, 0};
#pragma unroll
    for (int db = 0; db < 8; ++db) {
        int e = db * 16 + c15;
#pragma unroll
        for (int r = 0; r < 4; ++r) {
            float v = acc[db][r] + Qe[(size_t)(R0 + r) * 128 + e];
            x[db][r] = v;
            sum[r] += v;
            sq[r] += v * v;
        }
    }
#pragma unroll
    for (int r = 0; r < 4; ++r) {
#pragma unroll
        for (int dd = 1; dd < 16; dd <<= 1) {
            sum[r] += __shfl_xor(sum[r], dd);
            sq[r]  += __shfl_xor(sq[r], dd);
        }
    }
#pragma unroll
    for (int db = 0; db < 8; ++db) {
        int e = db * 16 + c15;
        float gg = ln_g[e], bb = ln_b[e];
#pragma unroll
        for (int r = 0; r < 4; ++r) {
            float mean = sum[r] * (1.0f / 128.0f);
            float var = sq[r] * (1.0f / 128.0f) - mean * mean;
            float rstd = rsqrtf(var + 1e-6f);
            out[(size_t)(R0 + r) * 128 + e] = (x[db][r] - mean) * rstd * gg + bb;
        }
    }
}

// ---------- launcher ----------
extern "C" void kernel_launch(void* const* d_in, const int* in_sizes, int n_in,
                              void* d_out, int out_size, void* d_ws, size_t ws_size,
                              hipStream_t stream) {
    const float* Q     = (const float*)d_in[0];
    const float* K     = (const float*)d_in[1];
    const float* V     = (const float*)d_in[2];
    const float* QMask = (const float*)d_in[3];
    const float* W_in  = (const float*)d_in[4];
    const float* W_mh  = (const float*)d_in[5];
    const float* W_fc  = (const float*)d_in[6];
    const float* ln_g  = (const float*)d_in[7];
    const float* ln_b  = (const float*)d_in[8];
    float* out = (float*)d_out;

    char* ws = (char*)d_ws;
    u16*   wcomb = (u16*)(ws);                   // 131072 B
    u16*   wfc16 = (u16*)(ws + 131072);          // 262144 B
    float* Qe    = (float*)(ws + 393216);        // 8388608 B
    u16*   qb    = (u16*)(ws + 8781824);         // [B*H,S,128] bf16, q pre-scaled
    u16*   kb    = (u16*)(ws + 42336256);        // compacted K rows
    u16*   vT    = (u16*)(ws + 75890688);        // [B*H,128,S] compacted V^T
    u16*   mha   = (u16*)(ws + 109445120);       // attn out; aliases vrow (pre-attn)
    u16*   vrow  = mha;                          // compacted V rows (consumed by vtrans)
    u16*   pos   = (u16*)(ws + 142999552);       // [B,S] compact position or 0xFFFF
    int*   cnt   = (int*)(ws + 143032320);       // [B] unmasked counts

    hipLaunchKernelGGL(prep_kernel, dim3(768), dim3(256), 0, stream,
                       W_in, W_mh, W_fc, wcomb, wfc16);
    hipLaunchKernelGGL(mask_scan, dim3(8), dim3(64), 0, stream, QMask, pos, cnt);
    hipLaunchKernelGGL(qe_kernel, dim3(8192), dim3(256), 0, stream, Q, W_in, Qe);
    hipLaunchKernelGGL(qkv_kernel, dim3(256, 4, 3), dim3(256), 0, stream,
                       Q, K, V, wcomb, pos, qb, kb, vrow);
    hipLaunchKernelGGL(vtrans_kernel, dim3(32, 64), dim3(256), 0, stream,
                       vrow, cnt, vT);
    hipLaunchKernelGGL(attn_kernel, dim3(32, 8, 8), dim3(256), 0, stream,
                       qb, kb, vT, cnt, mha);
    hipLaunchKernelGGL(final_kernel, dim3(256), dim3(256), 0, stream,
                       mha, wfc16, Qe, ln_g, ln_b, out);
}

// Round 3
// 231.721 us; speedup vs baseline: 2.3112x; 1.6878x over previous
//
#include <hip/hip_runtime.h>
#include <hip/hip_bf16.h>
#include <cstdint>

typedef __attribute__((ext_vector_type(8))) short short8;
typedef __attribute__((ext_vector_type(4))) float f32x4;
typedef __attribute__((ext_vector_type(16))) float f32x16;
typedef unsigned short u16;
typedef unsigned int u32;

__device__ __forceinline__ u16 f2bf(float f) {
    union { float f; u32 u; } v; v.f = f;
    u32 u = v.u;
    u = (u + 0x7fffu + ((u >> 16) & 1u)) >> 16;
    return (u16)u;
}

__device__ __forceinline__ u32 pk_bf16(float lo, float hi) {
    u32 r;
    asm("v_cvt_pk_bf16_f32 %0, %1, %2" : "=v"(r) : "v"(lo), "v"(hi));
    return r;
}

// swap(a.hi, b.lo): a' = {a.lo, b.lo-from-partner}, b' = {a.hi, b.hi}
__device__ __forceinline__ void pl32swap(u32& a, u32& b) {
#if __has_builtin(__builtin_amdgcn_permlane32_swap)
    auto r = __builtin_amdgcn_permlane32_swap((int)a, (int)b, false, false);
    a = (u32)r[0]; b = (u32)r[1];
#else
    u32 ax = (u32)__shfl_xor((int)a, 32), bx = (u32)__shfl_xor((int)b, 32);
    bool hi = (threadIdx.x & 32) != 0;
    u32 na = hi ? bx : a;
    u32 nb = hi ? b : ax;
    a = na; b = nb;
#endif
}

__device__ __forceinline__ void gload_lds16(const u16* g, u16* l) {
    __builtin_amdgcn_global_load_lds((const __attribute__((address_space(1))) void*)g,
                                     (__attribute__((address_space(3))) void*)l, 16, 0, 0);
}

// build PV A-frag word set from 8 p-values (keys {0..3,8..11}+4*hi of a 16-key slice)
__device__ __forceinline__ short8 make_pa(float p0, float p1, float p2, float p3,
                                          float p4, float p5, float p6, float p7) {
    u32 a1 = pk_bf16(p0, p1), b1 = pk_bf16(p4, p5);
    u32 a2 = pk_bf16(p2, p3), b2 = pk_bf16(p6, p7);
    pl32swap(a1, b1); pl32swap(a2, b2);
    union { u32 w[4]; short8 s; } u;
    u.w[0] = a1; u.w[1] = a2; u.w[2] = b1; u.w[3] = b2;
    return u.s;
}

// ---------- kernel 0: W_comb = W_mh @ W_in (bf16), cast W_fc, W_in -> bf16 ----------
__global__ void prep_kernel(const float* __restrict__ W_in,
                            const float* __restrict__ W_mh,
                            const float* __restrict__ W_fc,
                            u16* __restrict__ wcomb, u16* __restrict__ wfc16,
                            u16* __restrict__ win16) {
    int idx = blockIdx.x * 256 + threadIdx.x;
    if (idx < 1024 * 64) {
        int f = idx >> 6, i = idx & 63;
        float acc = 0.f;
        for (int e = 0; e < 128; ++e)
            acc += W_mh[f * 128 + e] * W_in[e * 64 + i];
        wcomb[idx] = f2bf(acc);
    }
    int idx2 = idx - 65536;
    if (idx2 >= 0 && idx2 < 128 * 1024)
        wfc16[idx2] = f2bf(W_fc[idx2]);
    int idx3 = idx - 65536 - 131072;
    if (idx3 >= 0 && idx3 < 128 * 64)
        win16[idx3] = f2bf(W_in[idx3]);
}

// ---------- kernel 0b: per-batch stable compaction scan of QMask ----------
__global__ void mask_scan(const float* __restrict__ qmask,
                          u16* __restrict__ pos, int* __restrict__ cnt) {
    int b = blockIdx.x, t = threadIdx.x;
    int base = b * 2048 + t * 32;
    int c = 0;
#pragma unroll
    for (int i = 0; i < 32; ++i) c += (qmask[base + i] != 0.0f) ? 1 : 0;
    int inc = c;
#pragma unroll
    for (int dd = 1; dd < 64; dd <<= 1) {
        int v = __shfl_up(inc, dd);
        if (t >= dd) inc += v;
    }
    int run = inc - c;
#pragma unroll
    for (int i = 0; i < 32; ++i) {
        bool mk = (qmask[base + i] != 0.0f);
        pos[base + i] = mk ? (u16)run : (u16)0xFFFF;
        run += mk ? 1 : 0;
    }
    if (t == 63) cnt[b] = inc;
}

// ---------- kernel 1: Qe = Q @ W_in^T via MFMA (fp32 out, bf16 in) ----------
__global__ __launch_bounds__(256) void qe_kernel(const float* __restrict__ Q,
                                                 const u16* __restrict__ win16,
                                                 float* __restrict__ Qe) {
    int w = threadIdx.x >> 6, lane = threadIdx.x & 63;
    int g = lane >> 4, c15 = lane & 15;
    int Rrow = blockIdx.x * 64 + w * 16 + c15;
    short8 af[2];
#pragma unroll
    for (int c = 0; c < 2; ++c) {
        const float* p = Q + (size_t)Rrow * 64 + 8 * g + 32 * c;
        float4 fa = *(const float4*)(p);
        float4 fb = *(const float4*)(p + 4);
        short8 a;
        a[0] = (short)f2bf(fa.x); a[1] = (short)f2bf(fa.y);
        a[2] = (short)f2bf(fa.z); a[3] = (short)f2bf(fa.w);
        a[4] = (short)f2bf(fb.x); a[5] = (short)f2bf(fb.y);
        a[6] = (short)f2bf(fb.z); a[7] = (short)f2bf(fb.w);
        af[c] = a;
    }
    f32x4 acc[8];
#pragma unroll
    for (int i = 0; i < 8; ++i) acc[i] = {0.f, 0.f, 0.f, 0.f};
#pragma unroll
    for (int cb = 0; cb < 8; ++cb) {
        int col = cb * 16 + c15;
#pragma unroll
        for (int c = 0; c < 2; ++c) {
            short8 bfr = *(const short8*)(win16 + (size_t)col * 64 + 8 * g + 32 * c);
            acc[cb] = __builtin_amdgcn_mfma_f32_16x16x32_bf16(af[c], bfr, acc[cb], 0, 0, 0);
        }
    }
    int R0 = blockIdx.x * 64 + w * 16 + 4 * g;
#pragma unroll
    for (int cb = 0; cb < 8; ++cb)
#pragma unroll
        for (int r = 0; r < 4; ++r)
            Qe[(size_t)(R0 + r) * 128 + cb * 16 + c15] = acc[cb][r];
}

// ---------- kernel 2: q/k/v projections; q scaled by 1/sqrt(128); k,v compacted ----------
__global__ __launch_bounds__(256) void qkv_kernel(
    const float* __restrict__ Q, const float* __restrict__ K,
    const float* __restrict__ V, const u16* __restrict__ wcomb,
    const u16* __restrict__ pos,
    u16* __restrict__ qb, u16* __restrict__ kb, u16* __restrict__ vrow) {
    int w = threadIdx.x >> 6, lane = threadIdx.x & 63;
    int g = lane >> 4, c15 = lane & 15;
    int tensor = blockIdx.z;
    const float* X = tensor == 0 ? Q : (tensor == 1 ? K : V);

    int Rrow = blockIdx.x * 64 + w * 16 + c15;
    short8 af[2];
#pragma unroll
    for (int c = 0; c < 2; ++c) {
        const float* p = X + (size_t)Rrow * 64 + 8 * g + 32 * c;
        float4 fa = *(const float4*)(p);
        float4 fb = *(const float4*)(p + 4);
        short8 a;
        a[0] = (short)f2bf(fa.x); a[1] = (short)f2bf(fa.y);
        a[2] = (short)f2bf(fa.z); a[3] = (short)f2bf(fa.w);
        a[4] = (short)f2bf(fb.x); a[5] = (short)f2bf(fb.y);
        a[6] = (short)f2bf(fb.z); a[7] = (short)f2bf(fb.w);
        af[c] = a;
    }
    int colbase = blockIdx.y * 256;
    f32x4 acc[16];
#pragma unroll
    for (int i = 0; i < 16; ++i) acc[i] = {0.f, 0.f, 0.f, 0.f};
#pragma unroll
    for (int cb = 0; cb < 16; ++cb) {
        int col = colbase + cb * 16 + c15;
#pragma unroll
        for (int c = 0; c < 2; ++c) {
            short8 bfr = *(const short8*)(wcomb + (size_t)col * 64 + 8 * g + 32 * c);
            acc[cb] = __builtin_amdgcn_mfma_f32_16x16x32_bf16(af[c], bfr, acc[cb], 0, 0, 0);
        }
    }
    int Rbase = blockIdx.x * 64 + w * 16 + 4 * g;
    const float invT = 0.08838834764831845f;    // 1/sqrt(128)
    if (tensor == 0) {
#pragma unroll
        for (int cb = 0; cb < 16; ++cb) {
            int col = colbase + cb * 16 + c15;
            int h = col >> 7, d = col & 127;
#pragma unroll
            for (int r = 0; r < 4; ++r) {
                int R = Rbase + r;
                int b = R >> 11, s = R & 2047;
                qb[((size_t)(b * 8 + h) * 2048 + s) * 128 + d] = f2bf(acc[cb][r] * invT);
            }
        }
    } else {
        u16 pv[4];
#pragma unroll
        for (int r = 0; r < 4; ++r) pv[r] = pos[Rbase + r];
        u16* dstbuf = (tensor == 1) ? kb : vrow;
#pragma unroll
        for (int cb = 0; cb < 16; ++cb) {
            int col = colbase + cb * 16 + c15;
            int h = col >> 7, d = col & 127;
#pragma unroll
            for (int r = 0; r < 4; ++r) {
                if (pv[r] == 0xFFFF) continue;
                int b = (Rbase + r) >> 11;
                dstbuf[((size_t)(b * 8 + h) * 2048 + pv[r]) * 128 + d] = f2bf(acc[cb][r]);
            }
        }
    }
}

// ---------- kernel 2b: transpose compacted V rows -> vT[bh][128][2048] ----------
__global__ __launch_bounds__(256) void vtrans_kernel(
    const u16* __restrict__ vrow, const int* __restrict__ cnt,
    u16* __restrict__ vT) {
    int t = blockIdx.x, bh = blockIdx.y, b = bh >> 3;
    int L = cnt[b];
    if (t * 64 >= L) return;
    __shared__ __align__(16) u16 tile[64][136];
    const u16* src = vrow + ((size_t)bh * 2048 + t * 64) * 128;
#pragma unroll
    for (int i = 0; i < 4; ++i) {
        int chunk = threadIdx.x + i * 256;
        int row = chunk >> 4, cc = chunk & 15;
        uint4 val = {0, 0, 0, 0};
        if (t * 64 + row < L)                    // zero tail: NaN*0 would poison PV
            val = *(const uint4*)(src + (size_t)row * 128 + cc * 8);
        *(uint4*)(&tile[row][cc * 8]) = val;
    }
    __syncthreads();
    int d = threadIdx.x >> 1, half = threadIdx.x & 1;
    u16* dst = vT + ((size_t)bh * 128 + d) * 2048 + t * 64 + half * 32;
#pragma unroll
    for (int jc = 0; jc < 4; ++jc) {
        union { uint4 v; u16 s[8]; } u;
#pragma unroll
        for (int jj = 0; jj < 8; ++jj) u.s[jj] = tile[half * 32 + jc * 8 + jj][d];
        *(uint4*)(dst + jc * 8) = u.v;
    }
}

// ---------- kernel 3: flash attention, 8-wave 32x32 swapped-QK^T (m214 structure) ----------
__global__ __launch_bounds__(512, 2) void attn_kernel(
    const u16* __restrict__ qbuf, const u16* __restrict__ kbuf,
    const u16* __restrict__ vTbuf, const int* __restrict__ cnt,
    u16* __restrict__ mha) {
    __shared__ __align__(16) u16 kt[2][64 * 128];   // K tile, chunk-XOR via source
    __shared__ __align__(16) u16 vt[2][128 * 64];   // V^T tile

    const int w = threadIdx.x >> 6, lane = threadIdx.x & 63;
    const int hi = lane >> 5, l31 = lane & 31;
    const int bh = blockIdx.x, qt = blockIdx.y;     // bh fastest -> same bh per XCD
    const int b = bh >> 3, h = bh & 7;
    const int L = cnt[b];
    const int nt = (L + 63) >> 6;

    const u16* kbbh = kbuf + (size_t)bh * 2048 * 128;
    const u16* vTbh = vTbuf + (size_t)bh * 128 * 2048;

    // Q fragments (B-operand of swapped QK^T): q = qt*256 + w*32 + l31
    const int sgq = qt * 256 + w * 32 + l31;
    const u16* qrow = qbuf + ((size_t)bh * 2048 + sgq) * 128;
    short8 qf[8];
#pragma unroll
    for (int ds = 0; ds < 8; ++ds)
        qf[ds] = *(const short8*)(qrow + ds * 16 + hi * 8);

    f32x16 o0, o1, o2, o3;
#pragma unroll
    for (int r = 0; r < 16; ++r) { o0[r] = 0.f; o1[r] = 0.f; o2[r] = 0.f; o3[r] = 0.f; }
    float m = -1e30f, lsum = 0.f;

    auto stage = [&](int buf, int tt) {
#pragma unroll
        for (int c = 0; c < 2; ++c) {           // K: 4 rows per wave-call
            int rl = (c * 8 + w) * 4 + (lane >> 4);
            int chunk = (lane & 15) ^ (rl & 7);
            gload_lds16(kbbh + ((size_t)(tt * 64 + rl)) * 128 + chunk * 8,
                        &kt[buf][(c * 8 + w) * 512]);
        }
#pragma unroll
        for (int c = 0; c < 2; ++c) {           // V^T: 8 d-rows per wave-call
            int dl = (c * 8 + w) * 8 + (lane >> 3);
            int chunk = (lane & 7) ^ (dl & 7);
            gload_lds16(vTbh + (size_t)dl * 2048 + tt * 64 + chunk * 8,
                        &vt[buf][(c * 8 + w) * 512]);
        }
    };

    int cur = 0;
    stage(0, 0);
    __syncthreads();

    for (int t = 0; t < nt; ++t) {
        if (t + 1 < nt) stage(cur ^ 1, t + 1);
        const u16* ktb = kt[cur];
        const u16* vtb = vt[cur];

        // S^T = K . Q^T  (rows=keys, cols=q)
        f32x16 st0, st1;
#pragma unroll
        for (int r = 0; r < 16; ++r) { st0[r] = 0.f; st1[r] = 0.f; }
        int k0 = l31, k1 = 32 + l31;
#pragma unroll
        for (int ds = 0; ds < 8; ++ds) {
            int sw = ((ds * 2 + hi) ^ (l31 & 7)) << 3;
            short8 kf0 = *(const short8*)(ktb + (k0 << 7) + sw);
            short8 kf1 = *(const short8*)(ktb + (k1 << 7) + sw);
            st0 = __builtin_amdgcn_mfma_f32_32x32x16_bf16(kf0, qf[ds], st0, 0, 0, 0);
            st1 = __builtin_amdgcn_mfma_f32_32x32x16_bf16(kf1, qf[ds], st1, 0, 0, 0);
        }
        // tail mask: replace (kills garbage NaN/Inf too)
        if (t == nt - 1) {
#pragma unroll
            for (int r = 0; r < 16; ++r) {
                int kl = (r & 3) + 8 * (r >> 2) + 4 * hi;
                st0[r] = (t * 64 + kl < L) ? st0[r] : -1e30f;
                st1[r] = (t * 64 + 32 + kl < L) ? st1[r] : -1e30f;
            }
        }
        // row max (q = l31): in-register + partner half
        float mx = st0[0];
#pragma unroll
        for (int r = 1; r < 16; ++r) mx = fmaxf(mx, st0[r]);
#pragma unroll
        for (int r = 0; r < 16; ++r) mx = fmaxf(mx, st1[r]);
        mx = fmaxf(mx, __shfl_xor(mx, 32));
        // defer-max (THR=8)
        if (__any(mx - m > 8.0f)) {
            float mn = fmaxf(m, mx);
            float corr = __expf(m - mn);
            m = mn;
            lsum *= corr;
#pragma unroll
            for (int r = 0; r < 16; ++r) {
                float cc = __shfl(corr, (r & 3) + 8 * (r >> 2) + 4 * hi);
                o0[r] *= cc; o1[r] *= cc; o2[r] *= cc; o3[r] *= cc;
            }
        }
        // P = exp(S - m), row sum
        float p0a[16], p1a[16];
#pragma unroll
        for (int r = 0; r < 16; ++r) { p0a[r] = __expf(st0[r] - m); p1a[r] = __expf(st1[r] - m); }
        float s0 = 0.f, s1 = 0.f, s2 = 0.f, s3 = 0.f;
#pragma unroll
        for (int r = 0; r < 16; r += 4) {
            s0 += p0a[r]; s1 += p0a[r + 1]; s2 += p0a[r + 2]; s3 += p0a[r + 3];
            s0 += p1a[r]; s1 += p1a[r + 1]; s2 += p1a[r + 2]; s3 += p1a[r + 3];
        }
        float tot = (s0 + s1) + (s2 + s3);
        tot += __shfl_xor(tot, 32);
        lsum += tot;
        // P -> bf16 A-frags via cvt_pk + permlane32_swap (T12)
        short8 pa0 = make_pa(p0a[0], p0a[1], p0a[2], p0a[3], p0a[4], p0a[5], p0a[6], p0a[7]);
        short8 pa1 = make_pa(p0a[8], p0a[9], p0a[10], p0a[11], p0a[12], p0a[13], p0a[14], p0a[15]);
        short8 pa2 = make_pa(p1a[0], p1a[1], p1a[2], p1a[3], p1a[4], p1a[5], p1a[6], p1a[7]);
        short8 pa3 = make_pa(p1a[8], p1a[9], p1a[10], p1a[11], p1a[12], p1a[13], p1a[14], p1a[15]);
        // O += P @ V
#define VF(ks, dblk) (*(const short8*)(vtb + (((dblk) * 32 + l31) << 6) + (((((ks) * 2 + hi)) ^ (l31 & 7)) << 3)))
        o0 = __builtin_amdgcn_mfma_f32_32x32x16_bf16(pa0, VF(0, 0), o0, 0, 0, 0);
        o0 = __builtin_amdgcn_mfma_f32_32x32x16_bf16(pa1, VF(1, 0), o0, 0, 0, 0);
        o0 = __builtin_amdgcn_mfma_f32_32x32x16_bf16(pa2, VF(2, 0), o0, 0, 0, 0);
        o0 = __builtin_amdgcn_mfma_f32_32x32x16_bf16(pa3, VF(3, 0), o0, 0, 0, 0);
        o1 = __builtin_amdgcn_mfma_f32_32x32x16_bf16(pa0, VF(0, 1), o1, 0, 0, 0);
        o1 = __builtin_amdgcn_mfma_f32_32x32x16_bf16(pa1, VF(1, 1), o1, 0, 0, 0);
        o1 = __builtin_amdgcn_mfma_f32_32x32x16_bf16(pa2, VF(2, 1), o1, 0, 0, 0);
        o1 = __builtin_amdgcn_mfma_f32_32x32x16_bf16(pa3, VF(3, 1), o1, 0, 0, 0);
        o2 = __builtin_amdgcn_mfma_f32_32x32x16_bf16(pa0, VF(0, 2), o2, 0, 0, 0);
        o2 = __builtin_amdgcn_mfma_f32_32x32x16_bf16(pa1, VF(1, 2), o2, 0, 0, 0);
        o2 = __builtin_amdgcn_mfma_f32_32x32x16_bf16(pa2, VF(2, 2), o2, 0, 0, 0);
        o2 = __builtin_amdgcn_mfma_f32_32x32x16_bf16(pa3, VF(3, 2), o2, 0, 0, 0);
        o3 = __builtin_amdgcn_mfma_f32_32x32x16_bf16(pa0, VF(0, 3), o3, 0, 0, 0);
        o3 = __builtin_amdgcn_mfma_f32_32x32x16_bf16(pa1, VF(1, 3), o3, 0, 0, 0);
        o3 = __builtin_amdgcn_mfma_f32_32x32x16_bf16(pa2, VF(2, 3), o3, 0, 0, 0);
        o3 = __builtin_amdgcn_mfma_f32_32x32x16_bf16(pa3, VF(3, 3), o3, 0, 0, 0);
#undef VF
        __syncthreads();                        // drains prefetch + publishes buffer
        cur ^= 1;
    }
    // epilogue: normalize + scatter into "faithful reshape" layout
    float invl = 1.0f / lsum;
#pragma unroll
    for (int r = 0; r < 16; ++r) {
        int kl = (r & 3) + 8 * (r >> 2) + 4 * hi;
        float iv = __shfl(invl, kl);
        int sg = qt * 256 + w * 32 + kl;
        int srow = h * 256 + (sg >> 3);
        size_t base = ((size_t)b * 2048 + srow) * 1024 + (sg & 7) * 128 + l31;
        mha[base + 0]  = f2bf(o0[r] * iv);
        mha[base + 32] = f2bf(o1[r] * iv);
        mha[base + 64] = f2bf(o2[r] * iv);
        mha[base + 96] = f2bf(o3[r] * iv);
    }
}

// ---------- kernel 4: out = mha @ W_fc^T + Qe, then LayerNorm ----------
__global__ __launch_bounds__(256) void final_kernel(
    const u16* __restrict__ mha, const u16* __restrict__ wfc16,
    const float* __restrict__ Qe, const float* __restrict__ ln_g,
    const float* __restrict__ ln_b, float* __restrict__ out) {
    int w = threadIdx.x >> 6, lane = threadIdx.x & 63;
    int g = lane >> 4, c15 = lane & 15;
    int rbase = blockIdx.x * 64 + w * 16;
    f32x4 acc[8];
#pragma unroll
    for (int i = 0; i < 8; ++i) acc[i] = {0.f, 0.f, 0.f, 0.f};
    for (int kc = 0; kc < 32; ++kc) {
        short8 af = *(const short8*)(mha + (size_t)(rbase + c15) * 1024 + 8 * g + 32 * kc);
#pragma unroll
        for (int db = 0; db < 8; ++db) {
            short8 bfr = *(const short8*)(wfc16 + (size_t)(db * 16 + c15) * 1024 + 8 * g + 32 * kc);
            acc[db] = __builtin_amdgcn_mfma_f32_16x16x32_bf16(af, bfr, acc[db], 0, 0, 0);
        }
    }
    int R0 = rbase + 4 * g;
    float x[8][4];
    float sum[4] = {0, 0, 0, 0}, sq[4] = {0, 0, 0, 0};
#pragma unroll
    for (int db = 0; db < 8; ++db) {
        int e = db * 16 + c15;
#pragma unroll
        for (int r = 0; r < 4; ++r) {
            float v = acc[db][r] + Qe[(size_t)(R0 + r) * 128 + e];
            x[db][r] = v;
            sum[r] += v;
            sq[r] += v * v;
        }
    }
#pragma unroll
    for (int r = 0; r < 4; ++r) {
#pragma unroll
        for (int dd = 1; dd < 16; dd <<= 1) {
            sum[r] += __shfl_xor(sum[r], dd);
            sq[r]  += __shfl_xor(sq[r], dd);
        }
    }
#pragma unroll
    for (int db = 0; db < 8; ++db) {
        int e = db * 16 + c15;
        float gg = ln_g[e], bb = ln_b[e];
#pragma unroll
        for (int r = 0; r < 4; ++r) {
            float mean = sum[r] * (1.0f / 128.0f);
            float var = sq[r] * (1.0f / 128.0f) - mean * mean;
            float rstd = rsqrtf(var + 1e-6f);
            out[(size_t)(R0 + r) * 128 + e] = (x[db][r] - mean) * rstd * gg + bb;
        }
    }
}

// ---------- launcher ----------
extern "C" void kernel_launch(void* const* d_in, const int* in_sizes, int n_in,
                              void* d_out, int out_size, void* d_ws, size_t ws_size,
                              hipStream_t stream) {
    const float* Q     = (const float*)d_in[0];
    const float* K     = (const float*)d_in[1];
    const float* V     = (const float*)d_in[2];
    const float* QMask = (const float*)d_in[3];
    const float* W_in  = (const float*)d_in[4];
    const float* W_mh  = (const float*)d_in[5];
    const float* W_fc  = (const float*)d_in[6];
    const float* ln_g  = (const float*)d_in[7];
    const float* ln_b  = (const float*)d_in[8];
    float* out = (float*)d_out;

    char* ws = (char*)d_ws;
    u16*   wcomb = (u16*)(ws);                   // 131072 B
    u16*   wfc16 = (u16*)(ws + 131072);          // 262144 B
    float* Qe    = (float*)(ws + 393216);        // 8388608 B
    u16*   qb    = (u16*)(ws + 8781824);         // [B*H,S,128] bf16, q pre-scaled
    u16*   kb    = (u16*)(ws + 42336256);        // compacted K rows
    u16*   vT    = (u16*)(ws + 75890688);        // [B*H,128,S] compacted V^T
    u16*   mha   = (u16*)(ws + 109445120);       // attn out; aliases vrow (pre-attn)
    u16*   vrow  = mha;                          // compacted V rows (consumed by vtrans)
    u16*   pos   = (u16*)(ws + 142999552);       // [B,S] compact position or 0xFFFF
    int*   cnt   = (int*)(ws + 143032320);       // [B] unmasked counts
    u16*   win16 = (u16*)(ws + 143036416);       // W_in bf16 [128][64] = 16384 B

    hipLaunchKernelGGL(prep_kernel, dim3(800), dim3(256), 0, stream,
                       W_in, W_mh, W_fc, wcomb, wfc16, win16);
    hipLaunchKernelGGL(mask_scan, dim3(8), dim3(64), 0, stream, QMask, pos, cnt);
    hipLaunchKernelGGL(qe_kernel, dim3(256), dim3(256), 0, stream, Q, win16, Qe);
    hipLaunchKernelGGL(qkv_kernel, dim3(256, 4, 3), dim3(256), 0, stream,
                       Q, K, V, wcomb, pos, qb, kb, vrow);
    hipLaunchKernelGGL(vtrans_kernel, dim3(32, 64), dim3(256), 0, stream,
                       vrow, cnt, vT);
    hipLaunchKernelGGL(attn_kernel, dim3(64, 8), dim3(512), 0, stream,
                       qb, kb, vT, cnt, mha);
    hipLaunchKernelGGL(final_kernel, dim3(256), dim3(256), 0, stream,
                       mha, wfc16, Qe, ln_g, ln_b, out);
}

// Round 4
// 227.757 us; speedup vs baseline: 2.3514x; 1.0174x over previous
//
#include <hip/hip_runtime.h>
#include <hip/hip_bf16.h>
#include <cstdint>

typedef __attribute__((ext_vector_type(8))) short short8;
typedef __attribute__((ext_vector_type(4))) float f32x4;
typedef __attribute__((ext_vector_type(16))) float f32x16;
typedef unsigned short u16;
typedef unsigned int u32;

__device__ __forceinline__ u16 f2bf(float f) {
    union { float f; u32 u; } v; v.f = f;
    u32 u = v.u;
    u = (u + 0x7fffu + ((u >> 16) & 1u)) >> 16;
    return (u16)u;
}

__device__ __forceinline__ u32 pk_bf16(float lo, float hi) {
    u32 r;
    asm("v_cvt_pk_bf16_f32 %0, %1, %2" : "=v"(r) : "v"(lo), "v"(hi));
    return r;
}

__device__ __forceinline__ void pl32swap(u32& a, u32& b) {
#if __has_builtin(__builtin_amdgcn_permlane32_swap)
    auto r = __builtin_amdgcn_permlane32_swap((int)a, (int)b, false, false);
    a = (u32)r[0]; b = (u32)r[1];
#else
    u32 ax = (u32)__shfl_xor((int)a, 32), bx = (u32)__shfl_xor((int)b, 32);
    bool hi = (threadIdx.x & 32) != 0;
    u32 na = hi ? bx : a;
    u32 nb = hi ? b : ax;
    a = na; b = nb;
#endif
}

__device__ __forceinline__ void gload_lds16(const u16* g, u16* l) {
    __builtin_amdgcn_global_load_lds((const __attribute__((address_space(1))) void*)g,
                                     (__attribute__((address_space(3))) void*)l, 16, 0, 0);
}

// C-block rows (crow order) -> one 16-k A/B-frag via cvt_pk + permlane32_swap (T12)
__device__ __forceinline__ short8 make_pa(float p0, float p1, float p2, float p3,
                                          float p4, float p5, float p6, float p7) {
    u32 a1 = pk_bf16(p0, p1), b1 = pk_bf16(p4, p5);
    u32 a2 = pk_bf16(p2, p3), b2 = pk_bf16(p6, p7);
    pl32swap(a1, b1); pl32swap(a2, b2);
    union { u32 w[4]; short8 s; } u;
    u.w[0] = a1; u.w[1] = a2; u.w[2] = b1; u.w[3] = b2;
    return u.s;
}

// ---------- kernel 0: weights prep (blocks 0..799) + mask scan (blocks 800..807) ----------
__global__ void prep_kernel(const float* __restrict__ W_in,
                            const float* __restrict__ W_mh,
                            const float* __restrict__ W_fc,
                            const float* __restrict__ qmask,
                            u16* __restrict__ wcomb, u16* __restrict__ wfc16,
                            u16* __restrict__ win16,
                            u16* __restrict__ pos, int* __restrict__ cnt) {
    if (blockIdx.x >= 800) {                     // per-batch stable compaction scan
        if (threadIdx.x >= 64) return;
        int b = blockIdx.x - 800, t = threadIdx.x;
        int base = b * 2048 + t * 32;
        int c = 0;
#pragma unroll
        for (int i = 0; i < 32; ++i) c += (qmask[base + i] != 0.0f) ? 1 : 0;
        int inc = c;
#pragma unroll
        for (int dd = 1; dd < 64; dd <<= 1) {
            int v = __shfl_up(inc, dd);
            if (t >= dd) inc += v;
        }
        int run = inc - c;
#pragma unroll
        for (int i = 0; i < 32; ++i) {
            bool mk = (qmask[base + i] != 0.0f);
            pos[base + i] = mk ? (u16)run : (u16)0xFFFF;
            run += mk ? 1 : 0;
        }
        if (t == 63) cnt[b] = inc;
        return;
    }
    int idx = blockIdx.x * 256 + threadIdx.x;
    if (idx < 1024 * 64) {                       // W_comb = W_mh @ W_in
        int f = idx >> 6, i = idx & 63;
        float acc = 0.f;
        for (int e = 0; e < 128; ++e)
            acc += W_mh[f * 128 + e] * W_in[e * 64 + i];
        wcomb[idx] = f2bf(acc);
    }
    int idx2 = idx - 65536;
    if (idx2 >= 0 && idx2 < 128 * 1024)
        wfc16[idx2] = f2bf(W_fc[idx2]);
    int idx3 = idx - 65536 - 131072;
    if (idx3 >= 0 && idx3 < 128 * 64)
        win16[idx3] = f2bf(W_in[idx3]);
}

// ---------- kernel 1: k/v projections, compacted rows, LDS-staged 16B stores ----------
__global__ __launch_bounds__(256) void qkv_kernel(
    const float* __restrict__ K, const float* __restrict__ V,
    const u16* __restrict__ wcomb, const u16* __restrict__ pos,
    u16* __restrict__ kb, u16* __restrict__ vrow) {
    __shared__ __align__(16) u16 ot[64 * 264];
    int w = threadIdx.x >> 6, lane = threadIdx.x & 63;
    int g = lane >> 4, c15 = lane & 15;
    const float* X = blockIdx.z == 0 ? K : V;

    int Rrow = blockIdx.x * 64 + w * 16 + c15;
    short8 af[2];
#pragma unroll
    for (int c = 0; c < 2; ++c) {
        const float* p = X + (size_t)Rrow * 64 + 8 * g + 32 * c;
        float4 fa = *(const float4*)(p);
        float4 fb = *(const float4*)(p + 4);
        short8 a;
        a[0] = (short)f2bf(fa.x); a[1] = (short)f2bf(fa.y);
        a[2] = (short)f2bf(fa.z); a[3] = (short)f2bf(fa.w);
        a[4] = (short)f2bf(fb.x); a[5] = (short)f2bf(fb.y);
        a[6] = (short)f2bf(fb.z); a[7] = (short)f2bf(fb.w);
        af[c] = a;
    }
    int colbase = blockIdx.y * 256;
    f32x4 acc[16];
#pragma unroll
    for (int i = 0; i < 16; ++i) acc[i] = {0.f, 0.f, 0.f, 0.f};
#pragma unroll
    for (int cb = 0; cb < 16; ++cb) {
        int col = colbase + cb * 16 + c15;
#pragma unroll
        for (int c = 0; c < 2; ++c) {
            short8 bfr = *(const short8*)(wcomb + (size_t)col * 64 + 8 * g + 32 * c);
            acc[cb] = __builtin_amdgcn_mfma_f32_16x16x32_bf16(af[c], bfr, acc[cb], 0, 0, 0);
        }
    }
    int r0 = w * 16 + 4 * g;
#pragma unroll
    for (int cb = 0; cb < 16; ++cb)
#pragma unroll
        for (int r = 0; r < 4; ++r)
            ot[(r0 + r) * 264 + cb * 16 + c15] = f2bf(acc[cb][r]);
    __syncthreads();
    u16* dstbuf = blockIdx.z == 0 ? kb : vrow;
#pragma unroll
    for (int it = 0; it < 8; ++it) {
        int chunk = threadIdx.x + it * 256;
        int row = chunk >> 5, cc = chunk & 31;
        int R = blockIdx.x * 64 + row;
        u16 p = pos[R];
        if (p != 0xFFFF) {
            int b = R >> 11;
            int col0 = colbase + cc * 8;
            int h = col0 >> 7, d = col0 & 127;
            *(uint4*)(dstbuf + ((size_t)(b * 8 + h) * 2048 + p) * 128 + d) =
                *(const uint4*)(ot + row * 264 + cc * 8);
        }
    }
}

// ---------- kernel 2: transpose compacted V rows -> vT[bh][128][2048] ----------
__global__ __launch_bounds__(256) void vtrans_kernel(
    const u16* __restrict__ vrow, const int* __restrict__ cnt,
    u16* __restrict__ vT) {
    int t = blockIdx.x, bh = blockIdx.y, b = bh >> 3;
    int L = cnt[b];
    if (t * 64 >= L) return;
    __shared__ __align__(16) u16 tile[64][136];
    const u16* src = vrow + ((size_t)bh * 2048 + t * 64) * 128;
#pragma unroll
    for (int i = 0; i < 4; ++i) {
        int chunk = threadIdx.x + i * 256;
        int row = chunk >> 4, cc = chunk & 15;
        uint4 val = {0, 0, 0, 0};
        if (t * 64 + row < L)                    // zero tail: NaN*0 would poison PV
            val = *(const uint4*)(src + (size_t)row * 128 + cc * 8);
        *(uint4*)(&tile[row][cc * 8]) = val;
    }
    __syncthreads();
    int d = threadIdx.x >> 1, half = threadIdx.x & 1;
    u16* dst = vT + ((size_t)bh * 128 + d) * 2048 + t * 64 + half * 32;
#pragma unroll
    for (int jc = 0; jc < 4; ++jc) {
        union { uint4 v; u16 s[8]; } u;
#pragma unroll
        for (int jj = 0; jj < 8; ++jj) u.s[jj] = tile[half * 32 + jc * 8 + jj][d];
        *(uint4*)(dst + jc * 8) = u.v;
    }
}

// ---------- kernel 3: flash attention, fused q-projection, 8-wave 32x32 swapped-QK^T ----------
__global__ __launch_bounds__(512, 2) void attn_kernel(
    const float* __restrict__ Qin, const u16* __restrict__ wcomb,
    const u16* __restrict__ kbuf, const u16* __restrict__ vTbuf,
    const int* __restrict__ cnt, u16* __restrict__ mha) {
    __shared__ __align__(16) u16 kt[2][64 * 128];
    __shared__ __align__(16) u16 vt[2][128 * 64];

    const int w = threadIdx.x >> 6, lane = threadIdx.x & 63;
    const int hi = lane >> 5, l31 = lane & 31;
    const int bh = blockIdx.x, qt = blockIdx.y;  // id = bh + 64*qt -> XCD = bh%8
    const int b = bh >> 3, h = bh & 7;
    const int L = cnt[b];
    const int nt = (L + 63) >> 6;

    const u16* kbbh = kbuf + (size_t)bh * 2048 * 128;
    const u16* vTbh = vTbuf + (size_t)bh * 128 * 2048;

    auto stage = [&](int buf, int tt) {
#pragma unroll
        for (int c = 0; c < 2; ++c) {           // K: 4 rows per wave-call
            int rl = (c * 8 + w) * 4 + (lane >> 4);
            int chunk = (lane & 15) ^ (rl & 7);
            gload_lds16(kbbh + ((size_t)(tt * 64 + rl)) * 128 + chunk * 8,
                        &kt[buf][(c * 8 + w) * 512]);
        }
#pragma unroll
        for (int c = 0; c < 2; ++c) {           // V^T: 8 d-rows per wave-call
            int dl = (c * 8 + w) * 8 + (lane >> 3);
            int chunk = (lane & 7) ^ (dl & 7);
            gload_lds16(vTbh + (size_t)dl * 2048 + tt * 64 + chunk * 8,
                        &vt[buf][(c * 8 + w) * 512]);
        }
    };

    stage(0, 0);                                 // DMA overlaps q-projection below

    // ---- fused q-projection: qf = (Q_in @ wcomb_h^T) * invT, straight into B-frags ----
    const float invT = 0.08838834764831845f;     // 1/sqrt(128)
    const int sq = qt * 256 + w * 32 + l31;
    const float* qrow = Qin + ((size_t)b * 2048 + sq) * 64;
    short8 bq[4];
#pragma unroll
    for (int s = 0; s < 4; ++s) {
        const float* p = qrow + s * 16 + hi * 8;
        float4 fa = *(const float4*)(p);
        float4 fb = *(const float4*)(p + 4);
        short8 a;
        a[0] = (short)f2bf(fa.x); a[1] = (short)f2bf(fa.y);
        a[2] = (short)f2bf(fa.z); a[3] = (short)f2bf(fa.w);
        a[4] = (short)f2bf(fb.x); a[5] = (short)f2bf(fb.y);
        a[6] = (short)f2bf(fb.z); a[7] = (short)f2bf(fb.w);
        bq[s] = a;
    }
    short8 qf[8];
#pragma unroll
    for (int dblk = 0; dblk < 4; ++dblk) {
        f32x16 c2;
#pragma unroll
        for (int r = 0; r < 16; ++r) c2[r] = 0.f;
        const u16* wrow = wcomb + (size_t)(h * 128 + dblk * 32 + l31) * 64 + hi * 8;
#pragma unroll
        for (int s = 0; s < 4; ++s) {
            short8 wa = *(const short8*)(wrow + s * 16);
            c2 = __builtin_amdgcn_mfma_f32_32x32x16_bf16(wa, bq[s], c2, 0, 0, 0);
        }
        qf[2 * dblk] = make_pa(c2[0] * invT, c2[1] * invT, c2[2] * invT, c2[3] * invT,
                               c2[4] * invT, c2[5] * invT, c2[6] * invT, c2[7] * invT);
        qf[2 * dblk + 1] = make_pa(c2[8] * invT, c2[9] * invT, c2[10] * invT, c2[11] * invT,
                                   c2[12] * invT, c2[13] * invT, c2[14] * invT, c2[15] * invT);
    }

    f32x16 o0, o1, o2, o3;
#pragma unroll
    for (int r = 0; r < 16; ++r) { o0[r] = 0.f; o1[r] = 0.f; o2[r] = 0.f; o3[r] = 0.f; }
    float m = -1e30f, lsum = 0.f;

    int cur = 0;
    __syncthreads();

    for (int t = 0; t < nt; ++t) {
        if (t + 1 < nt) stage(cur ^ 1, t + 1);
        const u16* ktb = kt[cur];
        const u16* vtb = vt[cur];

        // S^T = K . Q^T
        f32x16 st0, st1;
#pragma unroll
        for (int r = 0; r < 16; ++r) { st0[r] = 0.f; st1[r] = 0.f; }
        int k0 = l31, k1 = 32 + l31;
        __builtin_amdgcn_s_setprio(1);
#pragma unroll
        for (int ds = 0; ds < 8; ++ds) {
            int sw = ((ds * 2 + hi) ^ (l31 & 7)) << 3;
            short8 kf0 = *(const short8*)(ktb + (k0 << 7) + sw);
            short8 kf1 = *(const short8*)(ktb + (k1 << 7) + sw);
            st0 = __builtin_amdgcn_mfma_f32_32x32x16_bf16(kf0, qf[ds], st0, 0, 0, 0);
            st1 = __builtin_amdgcn_mfma_f32_32x32x16_bf16(kf1, qf[ds], st1, 0, 0, 0);
        }
        __builtin_amdgcn_s_setprio(0);
        if (t == nt - 1) {                      // tail: replace (kills garbage NaN/Inf)
#pragma unroll
            for (int r = 0; r < 16; ++r) {
                int kl = (r & 3) + 8 * (r >> 2) + 4 * hi;
                st0[r] = (t * 64 + kl < L) ? st0[r] : -1e30f;
                st1[r] = (t * 64 + 32 + kl < L) ? st1[r] : -1e30f;
            }
        }
        float mx = st0[0];
#pragma unroll
        for (int r = 1; r < 16; ++r) mx = fmaxf(mx, st0[r]);
#pragma unroll
        for (int r = 0; r < 16; ++r) mx = fmaxf(mx, st1[r]);
        mx = fmaxf(mx, __shfl_xor(mx, 32));
        if (__any(mx - m > 8.0f)) {             // defer-max (THR=8)
            float mn = fmaxf(m, mx);
            float corr = __expf(m - mn);
            m = mn;
            lsum *= corr;
#pragma unroll
            for (int r = 0; r < 16; ++r) {
                float cc = __shfl(corr, (r & 3) + 8 * (r >> 2) + 4 * hi);
                o0[r] *= cc; o1[r] *= cc; o2[r] *= cc; o3[r] *= cc;
            }
        }
        float p0a[16], p1a[16];
#pragma unroll
        for (int r = 0; r < 16; ++r) { p0a[r] = __expf(st0[r] - m); p1a[r] = __expf(st1[r] - m); }
        float s0 = 0.f, s1 = 0.f, s2 = 0.f, s3 = 0.f;
#pragma unroll
        for (int r = 0; r < 16; r += 4) {
            s0 += p0a[r]; s1 += p0a[r + 1]; s2 += p0a[r + 2]; s3 += p0a[r + 3];
            s0 += p1a[r]; s1 += p1a[r + 1]; s2 += p1a[r + 2]; s3 += p1a[r + 3];
        }
        float tot = (s0 + s1) + (s2 + s3);
        tot += __shfl_xor(tot, 32);
        lsum += tot;
        short8 pa0 = make_pa(p0a[0], p0a[1], p0a[2], p0a[3], p0a[4], p0a[5], p0a[6], p0a[7]);
        short8 pa1 = make_pa(p0a[8], p0a[9], p0a[10], p0a[11], p0a[12], p0a[13], p0a[14], p0a[15]);
        short8 pa2 = make_pa(p1a[0], p1a[1], p1a[2], p1a[3], p1a[4], p1a[5], p1a[6], p1a[7]);
        short8 pa3 = make_pa(p1a[8], p1a[9], p1a[10], p1a[11], p1a[12], p1a[13], p1a[14], p1a[15]);
#define VF(ks, dblk) (*(const short8*)(vtb + (((dblk) * 32 + l31) << 6) + (((((ks) * 2 + hi)) ^ (l31 & 7)) << 3)))
        __builtin_amdgcn_s_setprio(1);
        o0 = __builtin_amdgcn_mfma_f32_32x32x16_bf16(pa0, VF(0, 0), o0, 0, 0, 0);
        o0 = __builtin_amdgcn_mfma_f32_32x32x16_bf16(pa1, VF(1, 0), o0, 0, 0, 0);
        o0 = __builtin_amdgcn_mfma_f32_32x32x16_bf16(pa2, VF(2, 0), o0, 0, 0, 0);
        o0 = __builtin_amdgcn_mfma_f32_32x32x16_bf16(pa3, VF(3, 0), o0, 0, 0, 0);
        o1 = __builtin_amdgcn_mfma_f32_32x32x16_bf16(pa0, VF(0, 1), o1, 0, 0, 0);
        o1 = __builtin_amdgcn_mfma_f32_32x32x16_bf16(pa1, VF(1, 1), o1, 0, 0, 0);
        o1 = __builtin_amdgcn_mfma_f32_32x32x16_bf16(pa2, VF(2, 1), o1, 0, 0, 0);
        o1 = __builtin_amdgcn_mfma_f32_32x32x16_bf16(pa3, VF(3, 1), o1, 0, 0, 0);
        o2 = __builtin_amdgcn_mfma_f32_32x32x16_bf16(pa0, VF(0, 2), o2, 0, 0, 0);
        o2 = __builtin_amdgcn_mfma_f32_32x32x16_bf16(pa1, VF(1, 2), o2, 0, 0, 0);
        o2 = __builtin_amdgcn_mfma_f32_32x32x16_bf16(pa2, VF(2, 2), o2, 0, 0, 0);
        o2 = __builtin_amdgcn_mfma_f32_32x32x16_bf16(pa3, VF(3, 2), o2, 0, 0, 0);
        o3 = __builtin_amdgcn_mfma_f32_32x32x16_bf16(pa0, VF(0, 3), o3, 0, 0, 0);
        o3 = __builtin_amdgcn_mfma_f32_32x32x16_bf16(pa1, VF(1, 3), o3, 0, 0, 0);
        o3 = __builtin_amdgcn_mfma_f32_32x32x16_bf16(pa2, VF(2, 3), o3, 0, 0, 0);
        o3 = __builtin_amdgcn_mfma_f32_32x32x16_bf16(pa3, VF(3, 3), o3, 0, 0, 0);
        __builtin_amdgcn_s_setprio(0);
#undef VF
        __syncthreads();
        cur ^= 1;
    }
    float invl = 1.0f / lsum;
#pragma unroll
    for (int r = 0; r < 16; ++r) {
        int kl = (r & 3) + 8 * (r >> 2) + 4 * hi;
        float iv = __shfl(invl, kl);
        int sg = qt * 256 + w * 32 + kl;
        int srow = h * 256 + (sg >> 3);
        size_t base = ((size_t)b * 2048 + srow) * 1024 + (sg & 7) * 128 + l31;
        mha[base + 0]  = f2bf(o0[r] * iv);
        mha[base + 32] = f2bf(o1[r] * iv);
        mha[base + 64] = f2bf(o2[r] * iv);
        mha[base + 96] = f2bf(o3[r] * iv);
    }
}

// ---------- kernel 4: out = mha @ W_fc^T + Q@W_in^T (residual), then LayerNorm ----------
__global__ __launch_bounds__(256) void final_kernel(
    const u16* __restrict__ mha, const u16* __restrict__ wfc16,
    const float* __restrict__ Qin, const u16* __restrict__ win16,
    const float* __restrict__ ln_g, const float* __restrict__ ln_b,
    float* __restrict__ out) {
    __shared__ __align__(16) float st[64 * 132];
    int w = threadIdx.x >> 6, lane = threadIdx.x & 63;
    int g = lane >> 4, c15 = lane & 15;
    int rbase = blockIdx.x * 64 + w * 16;
    f32x4 acc[8];
#pragma unroll
    for (int i = 0; i < 8; ++i) acc[i] = {0.f, 0.f, 0.f, 0.f};
    {   // residual Qe = Q @ W_in^T folded into the accumulator
        const float* p0 = Qin + (size_t)(rbase + c15) * 64;
        short8 af2[2];
#pragma unroll
        for (int c = 0; c < 2; ++c) {
            float4 fa = *(const float4*)(p0 + 8 * g + 32 * c);
            float4 fb = *(const float4*)(p0 + 8 * g + 32 * c + 4);
            short8 a;
            a[0] = (short)f2bf(fa.x); a[1] = (short)f2bf(fa.y);
            a[2] = (short)f2bf(fa.z); a[3] = (short)f2bf(fa.w);
            a[4] = (short)f2bf(fb.x); a[5] = (short)f2bf(fb.y);
            a[6] = (short)f2bf(fb.z); a[7] = (short)f2bf(fb.w);
            af2[c] = a;
        }
#pragma unroll
        for (int db = 0; db < 8; ++db)
#pragma unroll
            for (int c = 0; c < 2; ++c) {
                short8 bfr = *(const short8*)(win16 + (size_t)(db * 16 + c15) * 64 + 8 * g + 32 * c);
                acc[db] = __builtin_amdgcn_mfma_f32_16x16x32_bf16(af2[c], bfr, acc[db], 0, 0, 0);
            }
    }
    for (int kc = 0; kc < 32; ++kc) {
        short8 af = *(const short8*)(mha + (size_t)(rbase + c15) * 1024 + 8 * g + 32 * kc);
#pragma unroll
        for (int db = 0; db < 8; ++db) {
            short8 bfr = *(const short8*)(wfc16 + (size_t)(db * 16 + c15) * 1024 + 8 * g + 32 * kc);
            acc[db] = __builtin_amdgcn_mfma_f32_16x16x32_bf16(af, bfr, acc[db], 0, 0, 0);
        }
    }
    float sum[4] = {0, 0, 0, 0}, sq[4] = {0, 0, 0, 0};
#pragma unroll
    for (int db = 0; db < 8; ++db)
#pragma unroll
        for (int r = 0; r < 4; ++r) {
            float v = acc[db][r];
            sum[r] += v;
            sq[r] += v * v;
        }
#pragma unroll
    for (int r = 0; r < 4; ++r) {
#pragma unroll
        for (int dd = 1; dd < 16; dd <<= 1) {
            sum[r] += __shfl_xor(sum[r], dd);
            sq[r]  += __shfl_xor(sq[r], dd);
        }
    }
    int lr0 = w * 16 + 4 * g;
#pragma unroll
    for (int db = 0; db < 8; ++db) {
        int e = db * 16 + c15;
        float gg = ln_g[e], bb = ln_b[e];
#pragma unroll
        for (int r = 0; r < 4; ++r) {
            float mean = sum[r] * (1.0f / 128.0f);
            float var = sq[r] * (1.0f / 128.0f) - mean * mean;
            float rstd = rsqrtf(var + 1e-6f);
            st[(lr0 + r) * 132 + e] = (acc[db][r] - mean) * rstd * gg + bb;
        }
    }
    __syncthreads();
#pragma unroll
    for (int it = 0; it < 8; ++it) {
        int chunk = threadIdx.x + it * 256;
        int row = chunk >> 5, cc = chunk & 31;
        *(float4*)(out + (size_t)(blockIdx.x * 64 + row) * 128 + cc * 4) =
            *(const float4*)(st + row * 132 + cc * 4);
    }
}

// ---------- launcher ----------
extern "C" void kernel_launch(void* const* d_in, const int* in_sizes, int n_in,
                              void* d_out, int out_size, void* d_ws, size_t ws_size,
                              hipStream_t stream) {
    const float* Q     = (const float*)d_in[0];
    const float* K     = (const float*)d_in[1];
    const float* V     = (const float*)d_in[2];
    const float* QMask = (const float*)d_in[3];
    const float* W_in  = (const float*)d_in[4];
    const float* W_mh  = (const float*)d_in[5];
    const float* W_fc  = (const float*)d_in[6];
    const float* ln_g  = (const float*)d_in[7];
    const float* ln_b  = (const float*)d_in[8];
    float* out = (float*)d_out;

    char* ws = (char*)d_ws;
    u16*   wcomb = (u16*)(ws);                   // 131072 B
    u16*   wfc16 = (u16*)(ws + 131072);          // 262144 B
    u16*   kb    = (u16*)(ws + 42336256);        // compacted K rows [B*H,S,128]
    u16*   vT    = (u16*)(ws + 75890688);        // [B*H,128,S] compacted V^T
    u16*   mha   = (u16*)(ws + 109445120);       // attn out; aliases vrow (pre-attn)
    u16*   vrow  = mha;                          // compacted V rows (consumed by vtrans)
    u16*   pos   = (u16*)(ws + 142999552);       // [B,S] compact position or 0xFFFF
    int*   cnt   = (int*)(ws + 143032320);       // [B] unmasked counts
    u16*   win16 = (u16*)(ws + 143036416);       // W_in bf16 [128][64]

    hipLaunchKernelGGL(prep_kernel, dim3(808), dim3(256), 0, stream,
                       W_in, W_mh, W_fc, QMask, wcomb, wfc16, win16, pos, cnt);
    hipLaunchKernelGGL(qkv_kernel, dim3(256, 4, 2), dim3(256), 0, stream,
                       K, V, wcomb, pos, kb, vrow);
    hipLaunchKernelGGL(vtrans_kernel, dim3(32, 64), dim3(256), 0, stream,
                       vrow, cnt, vT);
    hipLaunchKernelGGL(attn_kernel, dim3(64, 8), dim3(512), 0, stream,
                       Q, wcomb, kb, vT, cnt, mha);
    hipLaunchKernelGGL(final_kernel, dim3(256), dim3(256), 0, stream,
                       mha, wfc16, Q, win16, ln_g, ln_b, out);
}

// Round 5
// 219.804 us; speedup vs baseline: 2.4365x; 1.0362x over previous
//
#include <hip/hip_runtime.h>
#include <hip/hip_bf16.h>
#include <cstdint>

typedef __attribute__((ext_vector_type(8))) short short8;
typedef __attribute__((ext_vector_type(4))) float f32x4;
typedef __attribute__((ext_vector_type(16))) float f32x16;
typedef unsigned short u16;
typedef unsigned int u32;

__device__ __forceinline__ u16 f2bf(float f) {
    union { float f; u32 u; } v; v.f = f;
    u32 u = v.u;
    u = (u + 0x7fffu + ((u >> 16) & 1u)) >> 16;
    return (u16)u;
}

__device__ __forceinline__ float fexp2(float x) {   // v_exp_f32 = 2^x
    float r;
    asm("v_exp_f32 %0, %1" : "=v"(r) : "v"(x));
    return r;
}

__device__ __forceinline__ u32 pk_bf16(float lo, float hi) {
    u32 r;
    asm("v_cvt_pk_bf16_f32 %0, %1, %2" : "=v"(r) : "v"(lo), "v"(hi));
    return r;
}

__device__ __forceinline__ void pl32swap(u32& a, u32& b) {
#if __has_builtin(__builtin_amdgcn_permlane32_swap)
    auto r = __builtin_amdgcn_permlane32_swap((int)a, (int)b, false, false);
    a = (u32)r[0]; b = (u32)r[1];
#else
    u32 ax = (u32)__shfl_xor((int)a, 32), bx = (u32)__shfl_xor((int)b, 32);
    bool hi = (threadIdx.x & 32) != 0;
    u32 na = hi ? bx : a;
    u32 nb = hi ? b : ax;
    a = na; b = nb;
#endif
}

__device__ __forceinline__ void gload_lds16(const u16* g, u16* l) {
    __builtin_amdgcn_global_load_lds((const __attribute__((address_space(1))) void*)g,
                                     (__attribute__((address_space(3))) void*)l, 16, 0, 0);
}

// C-block rows (crow order) -> one 16-k A/B-frag via cvt_pk + permlane32_swap (T12)
__device__ __forceinline__ short8 make_pa(float p0, float p1, float p2, float p3,
                                          float p4, float p5, float p6, float p7) {
    u32 a1 = pk_bf16(p0, p1), b1 = pk_bf16(p4, p5);
    u32 a2 = pk_bf16(p2, p3), b2 = pk_bf16(p6, p7);
    pl32swap(a1, b1); pl32swap(a2, b2);
    union { u32 w[4]; short8 s; } u;
    u.w[0] = a1; u.w[1] = a2; u.w[2] = b1; u.w[3] = b2;
    return u.s;
}

// ---------- kernel 0: weights prep (blocks 0..799) + mask scan (blocks 800..807) ----------
__global__ void prep_kernel(const float* __restrict__ W_in,
                            const float* __restrict__ W_mh,
                            const float* __restrict__ W_fc,
                            const float* __restrict__ qmask,
                            u16* __restrict__ wcomb, u16* __restrict__ wfc16,
                            u16* __restrict__ win16,
                            u16* __restrict__ pos, int* __restrict__ cnt) {
    if (blockIdx.x >= 800) {                     // per-batch stable compaction scan
        if (threadIdx.x >= 64) return;
        int b = blockIdx.x - 800, t = threadIdx.x;
        int base = b * 2048 + t * 32;
        int c = 0;
#pragma unroll
        for (int i = 0; i < 32; ++i) c += (qmask[base + i] != 0.0f) ? 1 : 0;
        int inc = c;
#pragma unroll
        for (int dd = 1; dd < 64; dd <<= 1) {
            int v = __shfl_up(inc, dd);
            if (t >= dd) inc += v;
        }
        int run = inc - c;
#pragma unroll
        for (int i = 0; i < 32; ++i) {
            bool mk = (qmask[base + i] != 0.0f);
            pos[base + i] = mk ? (u16)run : (u16)0xFFFF;
            run += mk ? 1 : 0;
        }
        if (t == 63) cnt[b] = inc;
        return;
    }
    int idx = blockIdx.x * 256 + threadIdx.x;
    if (idx < 1024 * 64) {                       // W_comb = W_mh @ W_in
        int f = idx >> 6, i = idx & 63;
        float acc = 0.f;
        for (int e = 0; e < 128; ++e)
            acc += W_mh[f * 128 + e] * W_in[e * 64 + i];
        wcomb[idx] = f2bf(acc);
    }
    int idx2 = idx - 65536;
    if (idx2 >= 0 && idx2 < 128 * 1024)
        wfc16[idx2] = f2bf(W_fc[idx2]);
    int idx3 = idx - 65536 - 131072;
    if (idx3 >= 0 && idx3 < 128 * 64)
        win16[idx3] = f2bf(W_in[idx3]);
}

// ---------- kernel 1: k/v projections, compacted rows, LDS-staged 16B stores ----------
__global__ __launch_bounds__(256) void qkv_kernel(
    const float* __restrict__ K, const float* __restrict__ V,
    const u16* __restrict__ wcomb, const u16* __restrict__ pos,
    u16* __restrict__ kb, u16* __restrict__ vrow) {
    __shared__ __align__(16) u16 ot[64 * 264];
    int w = threadIdx.x >> 6, lane = threadIdx.x & 63;
    int g = lane >> 4, c15 = lane & 15;
    const float* X = blockIdx.z == 0 ? K : V;

    int Rrow = blockIdx.x * 64 + w * 16 + c15;
    short8 af[2];
#pragma unroll
    for (int c = 0; c < 2; ++c) {
        const float* p = X + (size_t)Rrow * 64 + 8 * g + 32 * c;
        float4 fa = *(const float4*)(p);
        float4 fb = *(const float4*)(p + 4);
        short8 a;
        a[0] = (short)f2bf(fa.x); a[1] = (short)f2bf(fa.y);
        a[2] = (short)f2bf(fa.z); a[3] = (short)f2bf(fa.w);
        a[4] = (short)f2bf(fb.x); a[5] = (short)f2bf(fb.y);
        a[6] = (short)f2bf(fb.z); a[7] = (short)f2bf(fb.w);
        af[c] = a;
    }
    int colbase = blockIdx.y * 256;
    f32x4 acc[16];
#pragma unroll
    for (int i = 0; i < 16; ++i) acc[i] = {0.f, 0.f, 0.f, 0.f};
#pragma unroll
    for (int cb = 0; cb < 16; ++cb) {
        int col = colbase + cb * 16 + c15;
#pragma unroll
        for (int c = 0; c < 2; ++c) {
            short8 bfr = *(const short8*)(wcomb + (size_t)col * 64 + 8 * g + 32 * c);
            acc[cb] = __builtin_amdgcn_mfma_f32_16x16x32_bf16(af[c], bfr, acc[cb], 0, 0, 0);
        }
    }
    int r0 = w * 16 + 4 * g;
#pragma unroll
    for (int cb = 0; cb < 16; ++cb)
#pragma unroll
        for (int r = 0; r < 4; ++r)
            ot[(r0 + r) * 264 + cb * 16 + c15] = f2bf(acc[cb][r]);
    __syncthreads();
    u16* dstbuf = blockIdx.z == 0 ? kb : vrow;
#pragma unroll
    for (int it = 0; it < 8; ++it) {
        int chunk = threadIdx.x + it * 256;
        int row = chunk >> 5, cc = chunk & 31;
        int R = blockIdx.x * 64 + row;
        u16 p = pos[R];
        if (p != 0xFFFF) {
            int b = R >> 11;
            int col0 = colbase + cc * 8;
            int h = col0 >> 7, d = col0 & 127;
            *(uint4*)(dstbuf + ((size_t)(b * 8 + h) * 2048 + p) * 128 + d) =
                *(const uint4*)(ot + row * 264 + cc * 8);
        }
    }
}

// ---------- kernel 2: transpose compacted V rows -> vT[bh][128][2048] ----------
// row-pair interleave in regs -> XOR-swizzled ds_write_b32 -> ds_read_b128
__global__ __launch_bounds__(256) void vtrans_kernel(
    const u16* __restrict__ vrow, const int* __restrict__ cnt,
    u16* __restrict__ vT) {
    int t = blockIdx.x, bh = blockIdx.y, b = bh >> 3;
    int L = cnt[b];
    if (t * 64 >= L) return;
    __shared__ __align__(16) u32 tl[128 * 32];   // [d][32 s-pairs], chunk-XOR swizzled
    const u16* src = vrow + ((size_t)bh * 2048 + t * 64) * 128;
#pragma unroll
    for (int task = 0; task < 2; ++task) {
        int id = threadIdx.x + task * 256;       // 512 tasks: s-pair i x d-chunk c
        int i = id >> 4, c = id & 15;
        int r0 = 2 * i, r1 = 2 * i + 1;
        uint4 A = {0, 0, 0, 0}, Bv = {0, 0, 0, 0};
        if (t * 64 + r0 < L) A  = *(const uint4*)(src + (size_t)r0 * 128 + c * 8);
        if (t * 64 + r1 < L) Bv = *(const uint4*)(src + (size_t)r1 * 128 + c * 8);
        const u32* aw = (const u32*)&A;
        const u32* bw = (const u32*)&Bv;
#pragma unroll
        for (int j = 0; j < 4; ++j) {
            u32 lo  = (aw[j] & 0xFFFFu) | (bw[j] << 16);       // d=8c+2j,  rows (r0,r1)
            u32 hi2 = (aw[j] >> 16) | (bw[j] & 0xFFFF0000u);   // d=8c+2j+1
            int d0 = 8 * c + 2 * j, d1 = d0 + 1;
            int h0 = ((d0 & 7) ^ ((d0 >> 3) & 7)) << 2;
            int h1 = ((d1 & 7) ^ ((d1 >> 3) & 7)) << 2;
            tl[d0 * 32 + (i ^ h0)] = lo;
            tl[d1 * 32 + (i ^ h1)] = hi2;
        }
    }
    __syncthreads();
    int d = threadIdx.x >> 1, half = threadIdx.x & 1;
    int hd = (d & 7) ^ ((d >> 3) & 7);
    u16* dst = vT + ((size_t)bh * 128 + d) * 2048 + t * 64 + half * 32;
#pragma unroll
    for (int jc = 0; jc < 4; ++jc) {
        int chunk = (half * 4 + jc) ^ hd;
        *(uint4*)(dst + jc * 8) = *(const uint4*)(&tl[d * 32 + chunk * 4]);
    }
}

// ---------- kernel 3: flash attention, fused q-projection, 8-wave 32x32 swapped-QK^T ----------
__global__ __launch_bounds__(512, 2) void attn_kernel(
    const float* __restrict__ Qin, const u16* __restrict__ wcomb,
    const u16* __restrict__ kbuf, const u16* __restrict__ vTbuf,
    const int* __restrict__ cnt, u16* __restrict__ mha) {
    __shared__ __align__(16) u16 kt[2][64 * 128];
    __shared__ __align__(16) u16 vt[2][128 * 64];

    const int w = threadIdx.x >> 6, lane = threadIdx.x & 63;
    const int hi = lane >> 5, l31 = lane & 31;
    const int bh = blockIdx.x, qt = blockIdx.y;  // XCD = bh%8: all qt of a bh share L2
    const int b = bh >> 3, h = bh & 7;
    const int L = cnt[b];
    const int nt = (L + 63) >> 6;

    const u16* kbbh = kbuf + (size_t)bh * 2048 * 128;
    const u16* vTbh = vTbuf + (size_t)bh * 128 * 2048;

    auto stage = [&](int buf, int tt) {
#pragma unroll
        for (int c = 0; c < 2; ++c) {           // K: 4 rows per wave-call
            int rl = (c * 8 + w) * 4 + (lane >> 4);
            int chunk = (lane & 15) ^ (rl & 7);
            gload_lds16(kbbh + ((size_t)(tt * 64 + rl)) * 128 + chunk * 8,
                        &kt[buf][(c * 8 + w) * 512]);
        }
#pragma unroll
        for (int c = 0; c < 2; ++c) {           // V^T: 8 d-rows per wave-call
            int dl = (c * 8 + w) * 8 + (lane >> 3);
            int chunk = (lane & 7) ^ (dl & 7);
            gload_lds16(vTbh + (size_t)dl * 2048 + tt * 64 + chunk * 8,
                        &vt[buf][(c * 8 + w) * 512]);
        }
    };

    stage(0, 0);                                 // DMA overlaps q-projection below

    // ---- fused q-projection, scaled by log2(e)/sqrt(128) (softmax in log2 domain) ----
    const float invT2 = 0.12751743f;             // log2(e)/sqrt(128)
    const int sq = qt * 256 + w * 32 + l31;
    const float* qrow = Qin + ((size_t)b * 2048 + sq) * 64;
    short8 bq[4];
#pragma unroll
    for (int s = 0; s < 4; ++s) {
        const float* p = qrow + s * 16 + hi * 8;
        float4 fa = *(const float4*)(p);
        float4 fb = *(const float4*)(p + 4);
        short8 a;
        a[0] = (short)f2bf(fa.x); a[1] = (short)f2bf(fa.y);
        a[2] = (short)f2bf(fa.z); a[3] = (short)f2bf(fa.w);
        a[4] = (short)f2bf(fb.x); a[5] = (short)f2bf(fb.y);
        a[6] = (short)f2bf(fb.z); a[7] = (short)f2bf(fb.w);
        bq[s] = a;
    }
    short8 qf[8];
#pragma unroll
    for (int dblk = 0; dblk < 4; ++dblk) {
        f32x16 c2;
#pragma unroll
        for (int r = 0; r < 16; ++r) c2[r] = 0.f;
        const u16* wrow = wcomb + (size_t)(h * 128 + dblk * 32 + l31) * 64 + hi * 8;
#pragma unroll
        for (int s = 0; s < 4; ++s) {
            short8 wa = *(const short8*)(wrow + s * 16);
            c2 = __builtin_amdgcn_mfma_f32_32x32x16_bf16(wa, bq[s], c2, 0, 0, 0);
        }
        qf[2 * dblk] = make_pa(c2[0] * invT2, c2[1] * invT2, c2[2] * invT2, c2[3] * invT2,
                               c2[4] * invT2, c2[5] * invT2, c2[6] * invT2, c2[7] * invT2);
        qf[2 * dblk + 1] = make_pa(c2[8] * invT2, c2[9] * invT2, c2[10] * invT2, c2[11] * invT2,
                                   c2[12] * invT2, c2[13] * invT2, c2[14] * invT2, c2[15] * invT2);
    }

    f32x16 o0, o1, o2, o3;
#pragma unroll
    for (int r = 0; r < 16; ++r) { o0[r] = 0.f; o1[r] = 0.f; o2[r] = 0.f; o3[r] = 0.f; }
    float m = -1e30f, lsum = 0.f;

    int cur = 0;
    __syncthreads();

    for (int t = 0; t < nt; ++t) {
        if (t + 1 < nt) stage(cur ^ 1, t + 1);
        const u16* ktb = kt[cur];
        const u16* vtb = vt[cur];

        // S^T = K . Q^T  (log2 domain)
        f32x16 st0, st1;
#pragma unroll
        for (int r = 0; r < 16; ++r) { st0[r] = 0.f; st1[r] = 0.f; }
        int k0 = l31, k1 = 32 + l31;
#pragma unroll
        for (int ds = 0; ds < 8; ++ds) {
            int sw = ((ds * 2 + hi) ^ (l31 & 7)) << 3;
            short8 kf0 = *(const short8*)(ktb + (k0 << 7) + sw);
            short8 kf1 = *(const short8*)(ktb + (k1 << 7) + sw);
            st0 = __builtin_amdgcn_mfma_f32_32x32x16_bf16(kf0, qf[ds], st0, 0, 0, 0);
            st1 = __builtin_amdgcn_mfma_f32_32x32x16_bf16(kf1, qf[ds], st1, 0, 0, 0);
        }
        if (t == nt - 1) {                      // tail: replace (kills garbage NaN/Inf)
#pragma unroll
            for (int r = 0; r < 16; ++r) {
                int kl = (r & 3) + 8 * (r >> 2) + 4 * hi;
                st0[r] = (t * 64 + kl < L) ? st0[r] : -1e30f;
                st1[r] = (t * 64 + 32 + kl < L) ? st1[r] : -1e30f;
            }
        }
        float mx = st0[0];
#pragma unroll
        for (int r = 1; r < 16; ++r) mx = fmaxf(mx, st0[r]);
#pragma unroll
        for (int r = 0; r < 16; ++r) mx = fmaxf(mx, st1[r]);
        mx = fmaxf(mx, __shfl_xor(mx, 32));
        if (__any(mx - m > 11.0f)) {            // defer-max (log2 units)
            float mn = fmaxf(m, mx);
            float corr = fexp2(m - mn);
            m = mn;
            lsum *= corr;
#pragma unroll
            for (int r = 0; r < 16; ++r) {
                float cc = __shfl(corr, (r & 3) + 8 * (r >> 2) + 4 * hi);
                o0[r] *= cc; o1[r] *= cc; o2[r] *= cc; o3[r] *= cc;
            }
        }
        float p0a[16], p1a[16];
#pragma unroll
        for (int r = 0; r < 16; ++r) { p0a[r] = fexp2(st0[r] - m); p1a[r] = fexp2(st1[r] - m); }
        float s0 = 0.f, s1 = 0.f, s2 = 0.f, s3 = 0.f;
#pragma unroll
        for (int r = 0; r < 16; r += 4) {
            s0 += p0a[r]; s1 += p0a[r + 1]; s2 += p0a[r + 2]; s3 += p0a[r + 3];
            s0 += p1a[r]; s1 += p1a[r + 1]; s2 += p1a[r + 2]; s3 += p1a[r + 3];
        }
        float tot = (s0 + s1) + (s2 + s3);
        tot += __shfl_xor(tot, 32);
        lsum += tot;
        short8 pa0 = make_pa(p0a[0], p0a[1], p0a[2], p0a[3], p0a[4], p0a[5], p0a[6], p0a[7]);
        short8 pa1 = make_pa(p0a[8], p0a[9], p0a[10], p0a[11], p0a[12], p0a[13], p0a[14], p0a[15]);
        short8 pa2 = make_pa(p1a[0], p1a[1], p1a[2], p1a[3], p1a[4], p1a[5], p1a[6], p1a[7]);
        short8 pa3 = make_pa(p1a[8], p1a[9], p1a[10], p1a[11], p1a[12], p1a[13], p1a[14], p1a[15]);
#define VF(ks, dblk) (*(const short8*)(vtb + (((dblk) * 32 + l31) << 6) + (((((ks) * 2 + hi)) ^ (l31 & 7)) << 3)))
        o0 = __builtin_amdgcn_mfma_f32_32x32x16_bf16(pa0, VF(0, 0), o0, 0, 0, 0);
        o0 = __builtin_amdgcn_mfma_f32_32x32x16_bf16(pa1, VF(1, 0), o0, 0, 0, 0);
        o0 = __builtin_amdgcn_mfma_f32_32x32x16_bf16(pa2, VF(2, 0), o0, 0, 0, 0);
        o0 = __builtin_amdgcn_mfma_f32_32x32x16_bf16(pa3, VF(3, 0), o0, 0, 0, 0);
        o1 = __builtin_amdgcn_mfma_f32_32x32x16_bf16(pa0, VF(0, 1), o1, 0, 0, 0);
        o1 = __builtin_amdgcn_mfma_f32_32x32x16_bf16(pa1, VF(1, 1), o1, 0, 0, 0);
        o1 = __builtin_amdgcn_mfma_f32_32x32x16_bf16(pa2, VF(2, 1), o1, 0, 0, 0);
        o1 = __builtin_amdgcn_mfma_f32_32x32x16_bf16(pa3, VF(3, 1), o1, 0, 0, 0);
        o2 = __builtin_amdgcn_mfma_f32_32x32x16_bf16(pa0, VF(0, 2), o2, 0, 0, 0);
        o2 = __builtin_amdgcn_mfma_f32_32x32x16_bf16(pa1, VF(1, 2), o2, 0, 0, 0);
        o2 = __builtin_amdgcn_mfma_f32_32x32x16_bf16(pa2, VF(2, 2), o2, 0, 0, 0);
        o2 = __builtin_amdgcn_mfma_f32_32x32x16_bf16(pa3, VF(3, 2), o2, 0, 0, 0);
        o3 = __builtin_amdgcn_mfma_f32_32x32x16_bf16(pa0, VF(0, 3), o3, 0, 0, 0);
        o3 = __builtin_amdgcn_mfma_f32_32x32x16_bf16(pa1, VF(1, 3), o3, 0, 0, 0);
        o3 = __builtin_amdgcn_mfma_f32_32x32x16_bf16(pa2, VF(2, 3), o3, 0, 0, 0);
        o3 = __builtin_amdgcn_mfma_f32_32x32x16_bf16(pa3, VF(3, 3), o3, 0, 0, 0);
#undef VF
        __syncthreads();
        cur ^= 1;
    }
    float invl = 1.0f / lsum;
#pragma unroll
    for (int r = 0; r < 16; ++r) {
        int kl = (r & 3) + 8 * (r >> 2) + 4 * hi;
        float iv = __shfl(invl, kl);
        int sg = qt * 256 + w * 32 + kl;
        int srow = h * 256 + (sg >> 3);
        size_t base = ((size_t)b * 2048 + srow) * 1024 + (sg & 7) * 128 + l31;
        mha[base + 0]  = f2bf(o0[r] * iv);
        mha[base + 32] = f2bf(o1[r] * iv);
        mha[base + 64] = f2bf(o2[r] * iv);
        mha[base + 96] = f2bf(o3[r] * iv);
    }
}

// ---------- kernel 4: out = mha @ W_fc^T + Q@W_in^T (residual), then LayerNorm ----------
__global__ __launch_bounds__(256) void final_kernel(
    const u16* __restrict__ mha, const u16* __restrict__ wfc16,
    const float* __restrict__ Qin, const u16* __restrict__ win16,
    const float* __restrict__ ln_g, const float* __restrict__ ln_b,
    float* __restrict__ out) {
    __shared__ __align__(16) float st[64 * 132];
    int w = threadIdx.x >> 6, lane = threadIdx.x & 63;
    int g = lane >> 4, c15 = lane & 15;
    int rbase = blockIdx.x * 64 + w * 16;
    f32x4 acc[8];
#pragma unroll
    for (int i = 0; i < 8; ++i) acc[i] = {0.f, 0.f, 0.f, 0.f};
    {   // residual Qe = Q @ W_in^T folded into the accumulator
        const float* p0 = Qin + (size_t)(rbase + c15) * 64;
        short8 af2[2];
#pragma unroll
        for (int c = 0; c < 2; ++c) {
            float4 fa = *(const float4*)(p0 + 8 * g + 32 * c);
            float4 fb = *(const float4*)(p0 + 8 * g + 32 * c + 4);
            short8 a;
            a[0] = (short)f2bf(fa.x); a[1] = (short)f2bf(fa.y);
            a[2] = (short)f2bf(fa.z); a[3] = (short)f2bf(fa.w);
            a[4] = (short)f2bf(fb.x); a[5] = (short)f2bf(fb.y);
            a[6] = (short)f2bf(fb.z); a[7] = (short)f2bf(fb.w);
            af2[c] = a;
        }
#pragma unroll
        for (int db = 0; db < 8; ++db)
#pragma unroll
            for (int c = 0; c < 2; ++c) {
                short8 bfr = *(const short8*)(win16 + (size_t)(db * 16 + c15) * 64 + 8 * g + 32 * c);
                acc[db] = __builtin_amdgcn_mfma_f32_16x16x32_bf16(af2[c], bfr, acc[db], 0, 0, 0);
            }
    }
    for (int kc = 0; kc < 32; ++kc) {
        short8 af = *(const short8*)(mha + (size_t)(rbase + c15) * 1024 + 8 * g + 32 * kc);
#pragma unroll
        for (int db = 0; db < 8; ++db) {
            short8 bfr = *(const short8*)(wfc16 + (size_t)(db * 16 + c15) * 1024 + 8 * g + 32 * kc);
            acc[db] = __builtin_amdgcn_mfma_f32_16x16x32_bf16(af, bfr, acc[db], 0, 0, 0);
        }
    }
    float sum[4] = {0, 0, 0, 0}, sq[4] = {0, 0, 0, 0};
#pragma unroll
    for (int db = 0; db < 8; ++db)
#pragma unroll
        for (int r = 0; r < 4; ++r) {
            float v = acc[db][r];
            sum[r] += v;
            sq[r] += v * v;
        }
#pragma unroll
    for (int r = 0; r < 4; ++r) {
#pragma unroll
        for (int dd = 1; dd < 16; dd <<= 1) {
            sum[r] += __shfl_xor(sum[r], dd);
            sq[r]  += __shfl_xor(sq[r], dd);
        }
    }
    int lr0 = w * 16 + 4 * g;
#pragma unroll
    for (int db = 0; db < 8; ++db) {
        int e = db * 16 + c15;
        float gg = ln_g[e], bb = ln_b[e];
#pragma unroll
        for (int r = 0; r < 4; ++r) {
            float mean = sum[r] * (1.0f / 128.0f);
            float var = sq[r] * (1.0f / 128.0f) - mean * mean;
            float rstd = rsqrtf(var + 1e-6f);
            st[(lr0 + r) * 132 + e] = (acc[db][r] - mean) * rstd * gg + bb;
        }
    }
    __syncthreads();
#pragma unroll
    for (int it = 0; it < 8; ++it) {
        int chunk = threadIdx.x + it * 256;
        int row = chunk >> 5, cc = chunk & 31;
        *(float4*)(out + (size_t)(blockIdx.x * 64 + row) * 128 + cc * 4) =
            *(const float4*)(st + row * 132 + cc * 4);
    }
}

// ---------- launcher ----------
extern "C" void kernel_launch(void* const* d_in, const int* in_sizes, int n_in,
                              void* d_out, int out_size, void* d_ws, size_t ws_size,
                              hipStream_t stream) {
    const float* Q     = (const float*)d_in[0];
    const float* K     = (const float*)d_in[1];
    const float* V     = (const float*)d_in[2];
    const float* QMask = (const float*)d_in[3];
    const float* W_in  = (const float*)d_in[4];
    const float* W_mh  = (const float*)d_in[5];
    const float* W_fc  = (const float*)d_in[6];
    const float* ln_g  = (const float*)d_in[7];
    const float* ln_b  = (const float*)d_in[8];
    float* out = (float*)d_out;

    char* ws = (char*)d_ws;
    u16*   wcomb = (u16*)(ws);                   // 131072 B
    u16*   wfc16 = (u16*)(ws + 131072);          // 262144 B
    u16*   kb    = (u16*)(ws + 42336256);        // compacted K rows [B*H,S,128]
    u16*   vT    = (u16*)(ws + 75890688);        // [B*H,128,S] compacted V^T
    u16*   mha   = (u16*)(ws + 109445120);       // attn out; aliases vrow (pre-attn)
    u16*   vrow  = mha;                          // compacted V rows (consumed by vtrans)
    u16*   pos   = (u16*)(ws + 142999552);       // [B,S] compact position or 0xFFFF
    int*   cnt   = (int*)(ws + 143032320);       // [B] unmasked counts
    u16*   win16 = (u16*)(ws + 143036416);       // W_in bf16 [128][64]

    hipLaunchKernelGGL(prep_kernel, dim3(808), dim3(256), 0, stream,
                       W_in, W_mh, W_fc, QMask, wcomb, wfc16, win16, pos, cnt);
    hipLaunchKernelGGL(qkv_kernel, dim3(256, 4, 2), dim3(256), 0, stream,
                       K, V, wcomb, pos, kb, vrow);
    hipLaunchKernelGGL(vtrans_kernel, dim3(32, 64), dim3(256), 0, stream,
                       vrow, cnt, vT);
    hipLaunchKernelGGL(attn_kernel, dim3(64, 8), dim3(512), 0, stream,
                       Q, wcomb, kb, vT, cnt, mha);
    hipLaunchKernelGGL(final_kernel, dim3(256), dim3(256), 0, stream,
                       mha, wfc16, Q, win16, ln_g, ln_b, out);
}